// Round 9
// baseline (490.471 us; speedup 1.0000x reference)
//
#include <hip/hip_runtime.h>
#include <stdint.h>

typedef unsigned short u16;
typedef __bf16 bf16x8 __attribute__((ext_vector_type(8)));
typedef unsigned short u16x8 __attribute__((ext_vector_type(8)));
typedef float f32x4 __attribute__((ext_vector_type(4)));
typedef float f32x16 __attribute__((ext_vector_type(16)));

#define BSZ 2
#define SEQ 2048
#define DIM 1024
#define D_INNER 2048
#define DT_RANK 64
#define D_STATE 16
#define XPROJ_N 96   // DT_RANK + 2*D_STATE
#define NCHUNK 32
#define CHUNK_T 64   // SEQ / NCHUNK
#define LOG2E 1.44269504f

#define N_X   4194304
#define N_W   4194304
#define N_WX  196608
#define N_WDT 131072
#define N_WO  2097152
#define N_XD  393216

__device__ __forceinline__ float bf2f(u16 h) {
    return __uint_as_float(((unsigned)h) << 16);
}
__device__ __forceinline__ u16 f2bf(float f) {
    unsigned u = __float_as_uint(f);
    unsigned r = (u + 0x7FFFu + ((u >> 16) & 1u)) >> 16;
    return (u16)r;
}

__device__ __forceinline__ f32x4 mfma16(bf16x8 a, bf16x8 b, f32x4 c) {
    return __builtin_amdgcn_mfma_f32_16x16x32_bf16(a, b, c, 0, 0, 0);
}
__device__ __forceinline__ f32x16 mfma32(bf16x8 a, bf16x8 b, f32x16 c) {
    return __builtin_amdgcn_mfma_f32_32x32x16_bf16(a, b, c, 0, 0, 0);
}

__device__ __forceinline__ void gload_lds16(const void* g, void* l) {
    __builtin_amdgcn_global_load_lds(
        (const __attribute__((address_space(1))) unsigned int*)(uintptr_t)g,
        (__attribute__((address_space(3))) unsigned int*)(uintptr_t)l,
        16, 0, 0);
}

__device__ __forceinline__ void split1(const float* in, u16* hi, u16* lo, int i) {
    float v = in[i];
    u16 h = f2bf(v);
    hi[i] = h;
    lo[i] = f2bf(v - bf2f(h));
}

__global__ __launch_bounds__(256)
void megasplit4(const float* __restrict__ x,  u16* __restrict__ xh,  u16* __restrict__ xl,
                const float* __restrict__ w,  u16* __restrict__ wh,  u16* __restrict__ wl,
                const float* __restrict__ wx, u16* __restrict__ wxh, u16* __restrict__ wxl,
                const float* __restrict__ wd, u16* __restrict__ wdh, u16* __restrict__ wdl)
{
    int i = blockIdx.x * 256 + threadIdx.x;
    if (i < N_X) { split1(x, xh, xl, i); return; }
    i -= N_X;
    if (i < N_W) { split1(w, wh, wl, i); return; }
    i -= N_W;
    if (i < N_WX) { split1(wx, wxh, wxl, i); return; }
    i -= N_WX;
    if (i < N_WDT) { split1(wd, wdh, wdl, i); }
}

__global__ __launch_bounds__(256)
void split_kernel(const float* __restrict__ in, u16* __restrict__ hi,
                  u16* __restrict__ lo, int n)
{
    int i = blockIdx.x * 256 + threadIdx.x;
    if (i < n) split1(in, hi, lo, i);
}

enum { EPI_XZ = 0, EPI_F32 = 1, EPI_SOFTPLUS = 2 };

// 128x128 tile per 256-thread block, BK=32, global_load_lds staging, swizzled
// LDS, 32x32x16 MFMA (2x2 tiles of 32x32 per wave).
// TERMS=3: ah*bh+ah*bl+al*bh. TERMS=2: a*bh+a*bl.
template<int TERMS, int EPI>
__global__ __launch_bounds__(256)
void gemm128(const u16* __restrict__ Ah, const u16* __restrict__ Al, int lda,
             const u16* __restrict__ Bh, const u16* __restrict__ Bl, int ldb,
             void* __restrict__ C, void* __restrict__ C2, int ldc,
             int K, const float* __restrict__ bias)
{
    __shared__ u16 lds[(TERMS == 3) ? 16384 : 12288];
    u16* Ah_l = lds;
    u16* Al_l = lds + 4096;
    u16* Bh_l = lds + ((TERMS == 3) ? 8192 : 4096);
    u16* Bl_l = lds + ((TERMS == 3) ? 12288 : 8192);

    const int tid  = threadIdx.x;
    const int w    = tid >> 6;
    const int lane = tid & 63;
    const int l31  = lane & 31;
    const int lhi  = lane >> 5;          // 0/1: k-half within 16
    const int wr   = w >> 1;
    const int wc   = w & 1;
    const long m0  = (long)blockIdx.y * 128;
    const long n0  = (long)blockIdx.x * 128;

    const int c0 = w * 64 + lane;
    const int c1 = 256 + c0;
    const int ma0 = c0 >> 2, kca0 = ((c0 & 3) ^ ((ma0 >> 1) & 3)) * 8;
    const int ma1 = c1 >> 2, kca1 = ((c1 & 3) ^ ((ma1 >> 1) & 3)) * 8;

    const u16* Arow0 = Ah + (m0 + ma0) * (long)lda + kca0;
    const u16* Arow1 = Ah + (m0 + ma1) * (long)lda + kca1;
    const u16* Alrow0 = (TERMS == 3) ? Al + (m0 + ma0) * (long)lda + kca0 : nullptr;
    const u16* Alrow1 = (TERMS == 3) ? Al + (m0 + ma1) * (long)lda + kca1 : nullptr;
    const u16* Brow0 = Bh + (n0 + ma0) * (long)ldb + kca0;
    const u16* Brow1 = Bh + (n0 + ma1) * (long)ldb + kca1;
    const u16* Blrow0 = Bl + (n0 + ma0) * (long)ldb + kca0;
    const u16* Blrow1 = Bl + (n0 + ma1) * (long)ldb + kca1;

    f32x16 acc[2][2];
    #pragma unroll
    for (int i = 0; i < 2; i++)
        #pragma unroll
        for (int j = 0; j < 2; j++)
            #pragma unroll
            for (int r = 0; r < 16; r++) acc[i][j][r] = 0.f;

    // fragment LDS offsets: tile i (rows), substep s (k16): row m, kchunk 2s+lhi
    int aof[2][2], bof[2][2];
    #pragma unroll
    for (int i = 0; i < 2; i++) {
        int m = wr * 64 + i * 32 + l31;
        int n = wc * 64 + i * 32 + l31;
        #pragma unroll
        for (int s = 0; s < 2; s++) {
            int kc = 2 * s + lhi;
            aof[i][s] = (m * 4 + (kc ^ ((m >> 1) & 3))) * 8;
            bof[i][s] = (n * 4 + (kc ^ ((n >> 1) & 3))) * 8;
        }
    }

    for (int k0 = 0; k0 < K; k0 += 32) {
        __syncthreads();
        gload_lds16(Arow0 + k0, Ah_l + c0 * 8);
        gload_lds16(Arow1 + k0, Ah_l + c1 * 8);
        if (TERMS == 3) {
            gload_lds16(Alrow0 + k0, Al_l + c0 * 8);
            gload_lds16(Alrow1 + k0, Al_l + c1 * 8);
        }
        gload_lds16(Brow0 + k0, Bh_l + c0 * 8);
        gload_lds16(Brow1 + k0, Bh_l + c1 * 8);
        gload_lds16(Blrow0 + k0, Bl_l + c0 * 8);
        gload_lds16(Blrow1 + k0, Bl_l + c1 * 8);
        __syncthreads();

        #pragma unroll
        for (int s = 0; s < 2; s++) {
            bf16x8 fah[2], fal[2], fbh[2], fbl[2];
            #pragma unroll
            for (int i = 0; i < 2; i++) {
                fah[i] = *(const bf16x8*)(Ah_l + aof[i][s]);
                if (TERMS == 3) fal[i] = *(const bf16x8*)(Al_l + aof[i][s]);
                fbh[i] = *(const bf16x8*)(Bh_l + bof[i][s]);
                fbl[i] = *(const bf16x8*)(Bl_l + bof[i][s]);
            }
            #pragma unroll
            for (int i = 0; i < 2; i++) {
                #pragma unroll
                for (int j = 0; j < 2; j++) {
                    acc[i][j] = mfma32(fah[i], fbh[j], acc[i][j]);
                    acc[i][j] = mfma32(fah[i], fbl[j], acc[i][j]);
                    if (TERMS == 3) acc[i][j] = mfma32(fal[i], fbh[j], acc[i][j]);
                }
            }
        }
    }

    // C/D 32x32: col = lane&31, row = (reg&3) + 8*(reg>>2) + 4*(lane>>5)
    #pragma unroll
    for (int i = 0; i < 2; i++) {
        #pragma unroll
        for (int j = 0; j < 2; j++) {
            long col = n0 + wc * 64 + j * 32 + l31;
            #pragma unroll
            for (int r = 0; r < 16; r++) {
                long row = m0 + wr * 64 + i * 32 + (r & 3) + 8 * (r >> 2) + 4 * lhi;
                float x = acc[i][j][r];
                if (EPI == EPI_XZ) {
                    if (col < D_INNER) ((u16*)C)[row * (long)D_INNER + col] = f2bf(x);
                    else ((float*)C2)[row * (long)D_INNER + (col - D_INNER)] = x;
                } else if (EPI == EPI_SOFTPLUS) {
                    x += bias[col];
                    x = (x > 15.f) ? x : log1pf(__expf(x));
                    ((float*)C)[row * (long)ldc + col] = x;
                } else {
                    ((float*)C)[row * (long)ldc + col] = x;
                }
            }
        }
    }
}

// GEMM4 split-K=2: 128x128 tile, TERMS=2, 32x32x16 MFMA, partial f32 buffers
__global__ __launch_bounds__(256)
void gemm128_sk2(const u16* __restrict__ Ah, int lda,
                 const u16* __restrict__ Bh, const u16* __restrict__ Bl, int ldb,
                 float* __restrict__ OutBase, int ldc, int K0)
{
    __shared__ u16 lds[12288];
    u16* Ah_l = lds;
    u16* Bh_l = lds + 4096;
    u16* Bl_l = lds + 8192;

    const int tid  = threadIdx.x;
    const int w    = tid >> 6;
    const int lane = tid & 63;
    const int l31  = lane & 31;
    const int lhi  = lane >> 5;
    const int wr   = w >> 1;
    const int wc   = w & 1;
    const long m0  = (long)blockIdx.y * 128;
    const long n0  = (long)blockIdx.x * 128;
    const int kbase = blockIdx.z * K0;
    float* Out = OutBase + (long)blockIdx.z * 4194304;

    const int c0 = w * 64 + lane;
    const int c1 = 256 + c0;
    const int ma0 = c0 >> 2, kca0 = ((c0 & 3) ^ ((ma0 >> 1) & 3)) * 8;
    const int ma1 = c1 >> 2, kca1 = ((c1 & 3) ^ ((ma1 >> 1) & 3)) * 8;

    const u16* Arow0 = Ah + (m0 + ma0) * (long)lda + kbase + kca0;
    const u16* Arow1 = Ah + (m0 + ma1) * (long)lda + kbase + kca1;
    const u16* Brow0 = Bh + (n0 + ma0) * (long)ldb + kbase + kca0;
    const u16* Brow1 = Bh + (n0 + ma1) * (long)ldb + kbase + kca1;
    const u16* Blrow0 = Bl + (n0 + ma0) * (long)ldb + kbase + kca0;
    const u16* Blrow1 = Bl + (n0 + ma1) * (long)ldb + kbase + kca1;

    f32x16 acc[2][2];
    #pragma unroll
    for (int i = 0; i < 2; i++)
        #pragma unroll
        for (int j = 0; j < 2; j++)
            #pragma unroll
            for (int r = 0; r < 16; r++) acc[i][j][r] = 0.f;

    int aof[2][2], bof[2][2];
    #pragma unroll
    for (int i = 0; i < 2; i++) {
        int m = wr * 64 + i * 32 + l31;
        int n = wc * 64 + i * 32 + l31;
        #pragma unroll
        for (int s = 0; s < 2; s++) {
            int kc = 2 * s + lhi;
            aof[i][s] = (m * 4 + (kc ^ ((m >> 1) & 3))) * 8;
            bof[i][s] = (n * 4 + (kc ^ ((n >> 1) & 3))) * 8;
        }
    }

    for (int k0 = 0; k0 < K0; k0 += 32) {
        __syncthreads();
        gload_lds16(Arow0 + k0, Ah_l + c0 * 8);
        gload_lds16(Arow1 + k0, Ah_l + c1 * 8);
        gload_lds16(Brow0 + k0, Bh_l + c0 * 8);
        gload_lds16(Brow1 + k0, Bh_l + c1 * 8);
        gload_lds16(Blrow0 + k0, Bl_l + c0 * 8);
        gload_lds16(Blrow1 + k0, Bl_l + c1 * 8);
        __syncthreads();

        #pragma unroll
        for (int s = 0; s < 2; s++) {
            bf16x8 fah[2], fbh[2], fbl[2];
            #pragma unroll
            for (int i = 0; i < 2; i++) {
                fah[i] = *(const bf16x8*)(Ah_l + aof[i][s]);
                fbh[i] = *(const bf16x8*)(Bh_l + bof[i][s]);
                fbl[i] = *(const bf16x8*)(Bl_l + bof[i][s]);
            }
            #pragma unroll
            for (int i = 0; i < 2; i++) {
                #pragma unroll
                for (int j = 0; j < 2; j++) {
                    acc[i][j] = mfma32(fah[i], fbh[j], acc[i][j]);
                    acc[i][j] = mfma32(fah[i], fbl[j], acc[i][j]);
                }
            }
        }
    }

    #pragma unroll
    for (int i = 0; i < 2; i++) {
        #pragma unroll
        for (int j = 0; j < 2; j++) {
            long col = n0 + wc * 64 + j * 32 + l31;
            #pragma unroll
            for (int r = 0; r < 16; r++) {
                long row = m0 + wr * 64 + i * 32 + (r & 3) + 8 * (r >> 2) + 4 * lhi;
                Out[row * (long)ldc + col] = acc[i][j][r];
            }
        }
    }
}

// GEMM2 (K=64): 32x32 per wave, 3-term, softplus epilogue
__global__ __launch_bounds__(64)
void gemm_dt32(const u16* __restrict__ Ah, const u16* __restrict__ Al, int lda,
               const u16* __restrict__ Bh, const u16* __restrict__ Bl, int ldb,
               float* __restrict__ C, int ldc, const float* __restrict__ bias)
{
    const int lane = threadIdx.x;
    const int r16  = lane & 15;
    const int quad = lane >> 4;
    const long m0 = (long)blockIdx.y * 32;
    const long n0 = (long)blockIdx.x * 32;

    const u16* Ah0 = Ah + (m0 + r16) * (long)lda + quad * 8;
    const u16* Ah1 = Ah0 + 16L * lda;
    const u16* Al0 = Al + (m0 + r16) * (long)lda + quad * 8;
    const u16* Al1 = Al0 + 16L * lda;
    const u16* Bh0 = Bh + (n0 + r16) * (long)ldb + quad * 8;
    const u16* Bh1 = Bh0 + 16L * ldb;
    const u16* Bl0 = Bl + (n0 + r16) * (long)ldb + quad * 8;
    const u16* Bl1 = Bl0 + 16L * ldb;

    f32x4 acc00 = {0,0,0,0}, acc01 = {0,0,0,0}, acc10 = {0,0,0,0}, acc11 = {0,0,0,0};

    #pragma unroll
    for (int k = 0; k < DT_RANK; k += 32) {
        bf16x8 a0h = *(const bf16x8*)(Ah0 + k);
        bf16x8 a1h = *(const bf16x8*)(Ah1 + k);
        bf16x8 a0l = *(const bf16x8*)(Al0 + k);
        bf16x8 a1l = *(const bf16x8*)(Al1 + k);
        bf16x8 b0h = *(const bf16x8*)(Bh0 + k);
        bf16x8 b1h = *(const bf16x8*)(Bh1 + k);
        bf16x8 b0l = *(const bf16x8*)(Bl0 + k);
        bf16x8 b1l = *(const bf16x8*)(Bl1 + k);
        acc00 = mfma16(a0h, b0h, acc00); acc00 = mfma16(a0h, b0l, acc00); acc00 = mfma16(a0l, b0h, acc00);
        acc01 = mfma16(a0h, b1h, acc01); acc01 = mfma16(a0h, b1l, acc01); acc01 = mfma16(a0l, b1h, acc01);
        acc10 = mfma16(a1h, b0h, acc10); acc10 = mfma16(a1h, b0l, acc10); acc10 = mfma16(a1l, b0h, acc10);
        acc11 = mfma16(a1h, b1h, acc11); acc11 = mfma16(a1h, b1l, acc11); acc11 = mfma16(a1l, b1h, acc11);
    }

    #pragma unroll
    for (int i = 0; i < 2; i++) {
        #pragma unroll
        for (int j = 0; j < 2; j++) {
            f32x4 v = (i == 0) ? (j == 0 ? acc00 : acc01) : (j == 0 ? acc10 : acc11);
            long col = n0 + j * 16 + r16;
            #pragma unroll
            for (int r = 0; r < 4; r++) {
                long row = m0 + i * 16 + quad * 4 + r;
                float x = v[r] + bias[col];
                x = (x > 15.f) ? x : log1pf(__expf(x));
                C[row * (long)ldc + col] = x;
            }
        }
    }
}

// GEMM3: partial[kz] = u @ W_xproj^T over K-slice kz (no atomics)
__global__ __launch_bounds__(64)
void gemm3_skp(const u16* __restrict__ A, int lda,
               const u16* __restrict__ Bh, const u16* __restrict__ Bl, int ldb,
               float* __restrict__ Cpart, int ldc, int K0)
{
    const int lane = threadIdx.x;
    const int r16  = lane & 15;
    const int quad = lane >> 4;
    const long m0 = (long)blockIdx.y * 32;
    const long n0 = (long)blockIdx.x * 32;
    const int kbase = blockIdx.z * K0;
    float* C = Cpart + (long)blockIdx.z * N_XD;

    const u16* Ap0 = A  + (m0 + r16) * (long)lda + quad * 8 + kbase;
    const u16* Ap1 = Ap0 + 16L * lda;
    const u16* Bh0 = Bh + (n0 + r16) * (long)ldb + quad * 8 + kbase;
    const u16* Bh1 = Bh0 + 16L * ldb;
    const u16* Bl0 = Bl + (n0 + r16) * (long)ldb + quad * 8 + kbase;
    const u16* Bl1 = Bl0 + 16L * ldb;

    f32x4 acc00 = {0,0,0,0}, acc01 = {0,0,0,0}, acc10 = {0,0,0,0}, acc11 = {0,0,0,0};

    for (int k = 0; k < K0; k += 32) {
        bf16x8 a0 = *(const bf16x8*)(Ap0 + k);
        bf16x8 a1 = *(const bf16x8*)(Ap1 + k);
        bf16x8 b0h = *(const bf16x8*)(Bh0 + k);
        bf16x8 b1h = *(const bf16x8*)(Bh1 + k);
        bf16x8 b0l = *(const bf16x8*)(Bl0 + k);
        bf16x8 b1l = *(const bf16x8*)(Bl1 + k);
        acc00 = mfma16(a0, b0h, acc00); acc00 = mfma16(a0, b0l, acc00);
        acc01 = mfma16(a0, b1h, acc01); acc01 = mfma16(a0, b1l, acc01);
        acc10 = mfma16(a1, b0h, acc10); acc10 = mfma16(a1, b0l, acc10);
        acc11 = mfma16(a1, b1h, acc11); acc11 = mfma16(a1, b1l, acc11);
    }

    #pragma unroll
    for (int i = 0; i < 2; i++) {
        #pragma unroll
        for (int j = 0; j < 2; j++) {
            f32x4 v = (i == 0) ? (j == 0 ? acc00 : acc01) : (j == 0 ? acc10 : acc11);
            long col = n0 + j * 16 + r16;
            #pragma unroll
            for (int r = 0; r < 4; r++) {
                long row = m0 + i * 16 + quad * 4 + r;
                C[row * (long)ldc + col] = v[r];
            }
        }
    }
}

// combine 8 gemm3 partials -> xdbc f32 + hi/lo split
__global__ __launch_bounds__(256)
void combine3(const float* __restrict__ part, float* __restrict__ xdbc,
              u16* __restrict__ hi, u16* __restrict__ lo)
{
    int i = blockIdx.x * 256 + threadIdx.x;
    if (i >= N_XD) return;
    float s = 0.f;
    #pragma unroll
    for (int j = 0; j < 8; j++) s += part[(long)j * N_XD + i];
    xdbc[i] = s;
    u16 h = f2bf(s);
    hi[i] = h;
    lo[i] = f2bf(s - bf2f(h));
}

// depthwise causal conv(4) + bias + silu, 8 channels per thread
__global__ __launch_bounds__(256)
void conv_silu(const u16* __restrict__ xc, const float* __restrict__ cw,
               const float* __restrict__ cb, u16* __restrict__ u)
{
    long idx = ((long)blockIdx.x * 256 + threadIdx.x) * 8;
    int t  = (int)((idx >> 11) & 2047);
    int d0 = (int)(idx & 2047);

    bf16x8 xrow[4];
    #pragma unroll
    for (int j = 0; j < 4; j++) {
        int tt = t - 3 + j;
        if (tt >= 0) xrow[j] = *(const bf16x8*)(xc + idx + (long)(j - 3) * D_INNER);
        else         xrow[j] = bf16x8{0,0,0,0,0,0,0,0};
    }
    u16x8 out;
    #pragma unroll
    for (int e = 0; e < 8; e++) {
        int d = d0 + e;
        float acc = cb[d];
        #pragma unroll
        for (int j = 0; j < 4; j++)
            acc += cw[d * 4 + j] * (float)xrow[j][e];
        out[e] = f2bf(acc / (1.f + __expf(-acc)));
    }
    *(u16x8*)(u + idx) = out;
}

// ---- chunked parallel scan: pass A ----
__global__ __launch_bounds__(256)
void scan_partA(const float* __restrict__ delta, const u16* __restrict__ u,
                const float* __restrict__ xdbc, const float* __restrict__ A_log,
                float* __restrict__ hbuf, float* __restrict__ sdelta)
{
    const int d = blockIdx.x * 256 + threadIdx.x;
    const int c = blockIdx.y;
    const int b = blockIdx.z;
    const int t0 = c * CHUNK_T;

    float Af[16];
    #pragma unroll
    for (int s = 0; s < 16; s++) Af[s] = -__expf(A_log[d * 16 + s]) * LOG2E;

    float h[16];
    #pragma unroll
    for (int s = 0; s < 16; s++) h[s] = 0.f;
    float sd = 0.f;

    const float* dptr = delta + ((long)b * SEQ + t0) * D_INNER + d;
    const u16*   uptr = u     + ((long)b * SEQ + t0) * D_INNER + d;
    const float* xp   = xdbc  + ((long)b * SEQ + t0) * XPROJ_N;

    for (int t = 0; t < CHUNK_T; t++) {
        float dl = dptr[(long)t * D_INNER];
        float uu = bf2f(uptr[(long)t * D_INNER]);
        f32x4 B0 = *(const f32x4*)(xp + t * XPROJ_N + DT_RANK);
        f32x4 B1 = *(const f32x4*)(xp + t * XPROJ_N + DT_RANK + 4);
        f32x4 B2 = *(const f32x4*)(xp + t * XPROJ_N + DT_RANK + 8);
        f32x4 B3 = *(const f32x4*)(xp + t * XPROJ_N + DT_RANK + 12);
        float Bv[16] = {B0[0],B0[1],B0[2],B0[3], B1[0],B1[1],B1[2],B1[3],
                        B2[0],B2[1],B2[2],B2[3], B3[0],B3[1],B3[2],B3[3]};
        sd += dl;
        float dlu = dl * uu;
        #pragma unroll
        for (int s = 0; s < 16; s++)
            h[s] = h[s] * exp2f(dl * Af[s]) + dlu * Bv[s];
    }

    float* hout = hbuf + ((long)(b * NCHUNK + c) * D_INNER + d) * 16;
    #pragma unroll
    for (int s = 0; s < 16; s++) hout[s] = h[s];
    sdelta[(long)(b * NCHUNK + c) * D_INNER + d] = sd;
}

// ---- pass B: compose chunk boundaries (in-place: hbuf h_end -> h_in) ----
__global__ __launch_bounds__(256)
void scan_fixup(float* __restrict__ hbuf, const float* __restrict__ sdelta,
                const float* __restrict__ A_log)
{
    const int idx = blockIdx.x * 256 + threadIdx.x;
    const int ds = idx & (D_INNER * 16 - 1);
    const int b  = idx >> 15;
    const float Af = -__expf(A_log[ds]) * LOG2E;
    float hin = 0.f;
    #pragma unroll 4
    for (int c = 0; c < NCHUNK; c++) {
        long gi = (long)(b * NCHUNK + c) * (D_INNER * 16) + ds;
        float e = hbuf[gi];
        hbuf[gi] = hin;
        float sd = sdelta[(long)(b * NCHUNK + c) * D_INNER + (ds >> 4)];
        hin = e + exp2f(Af * sd) * hin;
    }
}

// ---- pass C: full scan from h_in, fused +u*D and *silu(z), write y (bf16) ----
__global__ __launch_bounds__(256)
void scan_partC(const float* __restrict__ delta, const u16* __restrict__ u,
                const float* __restrict__ xdbc, const float* __restrict__ z,
                const float* __restrict__ A_log, const float* __restrict__ Dp,
                const float* __restrict__ hbuf, u16* __restrict__ y)
{
    const int d = blockIdx.x * 256 + threadIdx.x;
    const int c = blockIdx.y;
    const int b = blockIdx.z;
    const int t0 = c * CHUNK_T;

    float Af[16];
    #pragma unroll
    for (int s = 0; s < 16; s++) Af[s] = -__expf(A_log[d * 16 + s]) * LOG2E;
    const float Dd = Dp[d];

    float h[16];
    const float* hin = hbuf + ((long)(b * NCHUNK + c) * D_INNER + d) * 16;
    #pragma unroll
    for (int s = 0; s < 16; s++) h[s] = hin[s];

    const float* dptr = delta + ((long)b * SEQ + t0) * D_INNER + d;
    const u16*   uptr = u     + ((long)b * SEQ + t0) * D_INNER + d;
    const float* zptr = z     + ((long)b * SEQ + t0) * D_INNER + d;
    const float* xp   = xdbc  + ((long)b * SEQ + t0) * XPROJ_N;
    u16* yptr = y + ((long)b * SEQ + t0) * D_INNER + d;

    for (int t = 0; t < CHUNK_T; t++) {
        float dl = dptr[(long)t * D_INNER];
        float uu = bf2f(uptr[(long)t * D_INNER]);
        float zl = zptr[(long)t * D_INNER];
        f32x4 B0 = *(const f32x4*)(xp + t * XPROJ_N + DT_RANK);
        f32x4 B1 = *(const f32x4*)(xp + t * XPROJ_N + DT_RANK + 4);
        f32x4 B2 = *(const f32x4*)(xp + t * XPROJ_N + DT_RANK + 8);
        f32x4 B3 = *(const f32x4*)(xp + t * XPROJ_N + DT_RANK + 12);
        f32x4 C0 = *(const f32x4*)(xp + t * XPROJ_N + DT_RANK + 16);
        f32x4 C1 = *(const f32x4*)(xp + t * XPROJ_N + DT_RANK + 20);
        f32x4 C2 = *(const f32x4*)(xp + t * XPROJ_N + DT_RANK + 24);
        f32x4 C3 = *(const f32x4*)(xp + t * XPROJ_N + DT_RANK + 28);
        float Bv[16] = {B0[0],B0[1],B0[2],B0[3], B1[0],B1[1],B1[2],B1[3],
                        B2[0],B2[1],B2[2],B2[3], B3[0],B3[1],B3[2],B3[3]};
        float Cv[16] = {C0[0],C0[1],C0[2],C0[3], C1[0],C1[1],C1[2],C1[3],
                        C2[0],C2[1],C2[2],C2[3], C3[0],C3[1],C3[2],C3[3]};
        float dlu = dl * uu;
        float p0 = 0.f, p1 = 0.f, p2 = 0.f, p3 = 0.f;
        #pragma unroll
        for (int s = 0; s < 16; s += 4) {
            h[s]   = h[s]   * exp2f(dl * Af[s])   + dlu * Bv[s];
            h[s+1] = h[s+1] * exp2f(dl * Af[s+1]) + dlu * Bv[s+1];
            h[s+2] = h[s+2] * exp2f(dl * Af[s+2]) + dlu * Bv[s+2];
            h[s+3] = h[s+3] * exp2f(dl * Af[s+3]) + dlu * Bv[s+3];
            p0 += h[s]   * Cv[s];
            p1 += h[s+1] * Cv[s+1];
            p2 += h[s+2] * Cv[s+2];
            p3 += h[s+3] * Cv[s+3];
        }
        float acc = (p0 + p1) + (p2 + p3);
        float sz = zl / (1.f + __expf(-zl));
        float yy = (acc + uu * Dd) * sz;
        yptr[(long)t * D_INNER] = f2bf(yy);
    }
}

// layernorm over sum of 2 split-K partials
__global__ __launch_bounds__(256)
void layernorm_kernel(const float* __restrict__ pa, const float* __restrict__ pb,
                      const float* __restrict__ gamma, const float* __restrict__ beta,
                      float* __restrict__ out)
{
    const long row = blockIdx.x;
    const long base = row * DIM;
    int tid = threadIdx.x;
    float v[4];
    float sum = 0.f, sq = 0.f;
    #pragma unroll
    for (int i = 0; i < 4; i++) {
        long c = base + tid + i * 256;
        v[i] = pa[c] + pb[c];
        sum += v[i];
        sq  += v[i] * v[i];
    }
    #pragma unroll
    for (int off = 1; off < 64; off <<= 1) {
        sum += __shfl_xor(sum, off);
        sq  += __shfl_xor(sq, off);
    }
    __shared__ float ssum[4], ssq[4];
    int w = tid >> 6;
    if ((tid & 63) == 0) { ssum[w] = sum; ssq[w] = sq; }
    __syncthreads();
    float ts = ssum[0] + ssum[1] + ssum[2] + ssum[3];
    float tq = ssq[0] + ssq[1] + ssq[2] + ssq[3];
    float mean = ts * (1.f / DIM);
    float var  = tq * (1.f / DIM) - mean * mean;
    float rstd = rsqrtf(var + 1e-5f);
    float* o = out + base;
    #pragma unroll
    for (int i = 0; i < 4; i++) {
        int c = tid + i * 256;
        o[c] = (v[i] - mean) * rstd * gamma[c] + beta[c];
    }
}

extern "C" void kernel_launch(void* const* d_in, const int* in_sizes, int n_in,
                              void* d_out, int out_size, void* d_ws, size_t ws_size,
                              hipStream_t stream)
{
    const float* x      = (const float*)d_in[0];
    const float* W_in   = (const float*)d_in[1];
    const float* conv_w = (const float*)d_in[2];
    const float* conv_b = (const float*)d_in[3];
    const float* W_xproj= (const float*)d_in[4];
    const float* W_dt   = (const float*)d_in[5];
    const float* b_dt   = (const float*)d_in[6];
    const float* A_log  = (const float*)d_in[7];
    const float* Dv     = (const float*)d_in[8];
    const float* W_out  = (const float*)d_in[9];
    const float* gamma  = (const float*)d_in[10];
    const float* beta   = (const float*)d_in[11];

    char* ws = (char*)d_ws;
    u16*   xc    = (u16*)(ws);
    float* g3p   = (float*)(ws);
    u16*   xdh   = (u16*)(ws + 12582912);
    u16*   xdl   = (u16*)(ws + 14155776);
    float* hbuf  = (float*)(ws);
    float* sdel  = (float*)(ws + 8388608);
    float* z     = (float*)(ws + 16777216);
    float* opre  = (float*)(ws + 16777216);
    u16*   u     = (u16*)(ws + 50331648);
    u16*   wouth = (u16*)(ws + 50331648);
    u16*   woutl = (u16*)(ws + 54525952);
    u16*   xh    = (u16*)(ws + 67108864);
    u16*   xl    = (u16*)(ws + 75497472);
    u16*   wh    = (u16*)(ws + 83886080);
    u16*   wl    = (u16*)(ws + 92274688);
    float* delta = (float*)(ws + 67108864);
    float* xdbc  = (float*)(ws + 100663296);
    u16*   wxh   = (u16*)(ws + 102236160);
    u16*   wxl   = (u16*)(ws + 102629376);
    u16*   wdth  = (u16*)(ws + 103022592);
    u16*   wdtl  = (u16*)(ws + 103284736);
    u16*   yb    = (u16*)d_out;

    // 0) all pre-splits except W_out in one launch
    megasplit4<<<34048, 256, 0, stream>>>(x, xh, xl, W_in, wh, wl,
                                          W_xproj, wxh, wxl, W_dt, wdth, wdtl);
    // 1) xz = x @ W_in^T -> xc bf16 | z f32   (M=4096,N=4096,K=1024)
    gemm128<3, EPI_XZ><<<dim3(32, 32), 256, 0, stream>>>(
        xh, xl, DIM, wh, wl, DIM, xc, z, 0, DIM, nullptr);
    // 2) u = silu(conv4(xc)+cb)
    conv_silu<<<4096, 256, 0, stream>>>(xc, conv_w, conv_b, u);
    // 3) gemm3 partials (split-K=8) + combine(-> xdbc, xdh, xdl)
    gemm3_skp<<<dim3(3, 128, 8), 64, 0, stream>>>(
        u, D_INNER, wxh, wxl, D_INNER, g3p, XPROJ_N, 256);
    combine3<<<1536, 256, 0, stream>>>(g3p, xdbc, xdh, xdl);
    // 4) delta = softplus(dt @ W_dt^T + b_dt)  (M=4096,N=2048,K=64)
    gemm_dt32<<<dim3(64, 128), 64, 0, stream>>>(
        xdh, xdl, XPROJ_N, wdth, wdtl, DT_RANK, delta, D_INNER, b_dt);
    // 5) chunked parallel scan
    scan_partA<<<dim3(8, NCHUNK, BSZ), 256, 0, stream>>>(delta, u, xdbc, A_log, hbuf, sdel);
    scan_fixup<<<256, 256, 0, stream>>>(hbuf, sdel, A_log);
    scan_partC<<<dim3(8, NCHUNK, BSZ), 256, 0, stream>>>(delta, u, xdbc, z, A_log, Dv, hbuf, yb);
    // 5b) split W_out (into dead u region)
    split_kernel<<<8192, 256, 0, stream>>>(W_out, wouth, woutl, N_WO);
    // 6) opre[kz] = yb @ W_out^T slice  (split-K=2)
    gemm128_sk2<<<dim3(8, 32, 2), 256, 0, stream>>>(
        yb, D_INNER, wouth, woutl, D_INNER, opre, DIM, 1024);
    // 7) layernorm over sum of partials -> d_out f32
    layernorm_kernel<<<4096, 256, 0, stream>>>(
        opre, opre + 4194304, gamma, beta, (float*)d_out);
}

// Round 10
// 457.426 us; speedup vs baseline: 1.0722x; 1.0722x over previous
//
#include <hip/hip_runtime.h>
#include <stdint.h>

typedef unsigned short u16;
typedef __bf16 bf16x8 __attribute__((ext_vector_type(8)));
typedef unsigned short u16x8 __attribute__((ext_vector_type(8)));
typedef float f32x4 __attribute__((ext_vector_type(4)));

#define BSZ 2
#define SEQ 2048
#define DIM 1024
#define D_INNER 2048
#define DT_RANK 64
#define D_STATE 16
#define XPROJ_N 96   // DT_RANK + 2*D_STATE
#define NCHUNK 32
#define CHUNK_T 64   // SEQ / NCHUNK
#define LOG2E 1.44269504f

#define N_X   4194304
#define N_W   4194304
#define N_WX  196608
#define N_WDT 131072
#define N_WO  2097152
#define N_XD  393216

__device__ __forceinline__ float bf2f(u16 h) {
    return __uint_as_float(((unsigned)h) << 16);
}
__device__ __forceinline__ u16 f2bf(float f) {
    unsigned u = __float_as_uint(f);
    unsigned r = (u + 0x7FFFu + ((u >> 16) & 1u)) >> 16;
    return (u16)r;
}

__device__ __forceinline__ f32x4 mfma16(bf16x8 a, bf16x8 b, f32x4 c) {
    return __builtin_amdgcn_mfma_f32_16x16x32_bf16(a, b, c, 0, 0, 0);
}

__device__ __forceinline__ void gload_lds16(const void* g, void* l) {
    __builtin_amdgcn_global_load_lds(
        (const __attribute__((address_space(1))) unsigned int*)(uintptr_t)g,
        (__attribute__((address_space(3))) unsigned int*)(uintptr_t)l,
        16, 0, 0);
}

__device__ __forceinline__ void split1(const float* in, u16* hi, u16* lo, int i) {
    float v = in[i];
    u16 h = f2bf(v);
    hi[i] = h;
    lo[i] = f2bf(v - bf2f(h));
}

__global__ __launch_bounds__(256)
void megasplit4(const float* __restrict__ x,  u16* __restrict__ xh,  u16* __restrict__ xl,
                const float* __restrict__ w,  u16* __restrict__ wh,  u16* __restrict__ wl,
                const float* __restrict__ wx, u16* __restrict__ wxh, u16* __restrict__ wxl,
                const float* __restrict__ wd, u16* __restrict__ wdh, u16* __restrict__ wdl)
{
    int i = blockIdx.x * 256 + threadIdx.x;
    if (i < N_X) { split1(x, xh, xl, i); return; }
    i -= N_X;
    if (i < N_W) { split1(w, wh, wl, i); return; }
    i -= N_W;
    if (i < N_WX) { split1(wx, wxh, wxl, i); return; }
    i -= N_WX;
    if (i < N_WDT) { split1(wd, wdh, wdl, i); }
}

__global__ __launch_bounds__(256)
void split_kernel(const float* __restrict__ in, u16* __restrict__ hi,
                  u16* __restrict__ lo, int n)
{
    int i = blockIdx.x * 256 + threadIdx.x;
    if (i < n) split1(in, hi, lo, i);
}

enum { EPI_XZ = 0, EPI_F32 = 1, EPI_SOFTPLUS = 2 };

// 128x128 tile per 256-thread block, BK=32, global_load_lds staging, swizzled
// LDS, 16x16x32 MFMA (4x4 tiles of 16x16 per wave). PROVEN: 0 bank conflicts.
// (32x32x16 variant regressed: 8.4M conflicts — R9 post-mortem.)
// TERMS=3: ah*bh+ah*bl+al*bh. TERMS=2: a*bh+a*bl.
template<int TERMS, int EPI>
__global__ __launch_bounds__(256)
void gemm128(const u16* __restrict__ Ah, const u16* __restrict__ Al, int lda,
             const u16* __restrict__ Bh, const u16* __restrict__ Bl, int ldb,
             void* __restrict__ C, void* __restrict__ C2, int ldc,
             int K, const float* __restrict__ bias)
{
    __shared__ u16 lds[(TERMS == 3) ? 16384 : 12288];
    u16* Ah_l = lds;
    u16* Al_l = lds + 4096;
    u16* Bh_l = lds + ((TERMS == 3) ? 8192 : 4096);
    u16* Bl_l = lds + ((TERMS == 3) ? 12288 : 8192);

    const int tid  = threadIdx.x;
    const int w    = tid >> 6;
    const int lane = tid & 63;
    const int r16  = lane & 15;
    const int quad = lane >> 4;
    const int wr   = w >> 1;
    const int wc   = w & 1;
    const long m0  = (long)blockIdx.y * 128;
    const long n0  = (long)blockIdx.x * 128;

    const int c0 = w * 64 + lane;
    const int c1 = 256 + c0;
    const int ma0 = c0 >> 2, kca0 = ((c0 & 3) ^ ((ma0 >> 1) & 3)) * 8;
    const int ma1 = c1 >> 2, kca1 = ((c1 & 3) ^ ((ma1 >> 1) & 3)) * 8;

    const u16* Arow0 = Ah + (m0 + ma0) * (long)lda + kca0;
    const u16* Arow1 = Ah + (m0 + ma1) * (long)lda + kca1;
    const u16* Alrow0 = (TERMS == 3) ? Al + (m0 + ma0) * (long)lda + kca0 : nullptr;
    const u16* Alrow1 = (TERMS == 3) ? Al + (m0 + ma1) * (long)lda + kca1 : nullptr;
    const u16* Brow0 = Bh + (n0 + ma0) * (long)ldb + kca0;
    const u16* Brow1 = Bh + (n0 + ma1) * (long)ldb + kca1;
    const u16* Blrow0 = Bl + (n0 + ma0) * (long)ldb + kca0;
    const u16* Blrow1 = Bl + (n0 + ma1) * (long)ldb + kca1;

    f32x4 acc[4][4];
    #pragma unroll
    for (int i = 0; i < 4; i++)
        #pragma unroll
        for (int j = 0; j < 4; j++) acc[i][j] = {0.f, 0.f, 0.f, 0.f};

    int caof[4], cbof[4];
    #pragma unroll
    for (int i = 0; i < 4; i++) {
        int m = wr * 64 + i * 16 + r16;
        caof[i] = (m * 4 + (quad ^ ((m >> 1) & 3))) * 8;
        int n = wc * 64 + i * 16 + r16;
        cbof[i] = (n * 4 + (quad ^ ((n >> 1) & 3))) * 8;
    }

    for (int k0 = 0; k0 < K; k0 += 32) {
        __syncthreads();
        gload_lds16(Arow0 + k0, Ah_l + c0 * 8);
        gload_lds16(Arow1 + k0, Ah_l + c1 * 8);
        if (TERMS == 3) {
            gload_lds16(Alrow0 + k0, Al_l + c0 * 8);
            gload_lds16(Alrow1 + k0, Al_l + c1 * 8);
        }
        gload_lds16(Brow0 + k0, Bh_l + c0 * 8);
        gload_lds16(Brow1 + k0, Bh_l + c1 * 8);
        gload_lds16(Blrow0 + k0, Bl_l + c0 * 8);
        gload_lds16(Blrow1 + k0, Bl_l + c1 * 8);
        __syncthreads();

        bf16x8 fah[4], fal[4], fbh[4], fbl[4];
        #pragma unroll
        for (int i = 0; i < 4; i++) {
            fah[i] = *(const bf16x8*)(Ah_l + caof[i]);
            if (TERMS == 3) fal[i] = *(const bf16x8*)(Al_l + caof[i]);
            fbh[i] = *(const bf16x8*)(Bh_l + cbof[i]);
            fbl[i] = *(const bf16x8*)(Bl_l + cbof[i]);
        }
        #pragma unroll
        for (int i = 0; i < 4; i++) {
            #pragma unroll
            for (int j = 0; j < 4; j++) {
                acc[i][j] = mfma16(fah[i], fbh[j], acc[i][j]);
                acc[i][j] = mfma16(fah[i], fbl[j], acc[i][j]);
                if (TERMS == 3) acc[i][j] = mfma16(fal[i], fbh[j], acc[i][j]);
            }
        }
    }

    #pragma unroll
    for (int i = 0; i < 4; i++) {
        #pragma unroll
        for (int j = 0; j < 4; j++) {
            long col = n0 + wc * 64 + j * 16 + r16;
            #pragma unroll
            for (int r = 0; r < 4; r++) {
                long row = m0 + wr * 64 + i * 16 + quad * 4 + r;
                float x = acc[i][j][r];
                if (EPI == EPI_XZ) {
                    if (col < D_INNER) ((u16*)C)[row * (long)D_INNER + col] = f2bf(x);
                    else ((float*)C2)[row * (long)D_INNER + (col - D_INNER)] = x;
                } else if (EPI == EPI_SOFTPLUS) {
                    x += bias[col];
                    x = (x > 15.f) ? x : log1pf(__expf(x));
                    ((float*)C)[row * (long)ldc + col] = x;
                } else {
                    ((float*)C)[row * (long)ldc + col] = x;
                }
            }
        }
    }
}

// GEMM4 split-K=2: 128x128 tile, TERMS=2, kz slice -> own f32 partial buffer
__global__ __launch_bounds__(256)
void gemm128_sk2(const u16* __restrict__ Ah, int lda,
                 const u16* __restrict__ Bh, const u16* __restrict__ Bl, int ldb,
                 float* __restrict__ OutBase, int ldc, int K0)
{
    __shared__ u16 lds[12288];
    u16* Ah_l = lds;
    u16* Bh_l = lds + 4096;
    u16* Bl_l = lds + 8192;

    const int tid  = threadIdx.x;
    const int w    = tid >> 6;
    const int lane = tid & 63;
    const int r16  = lane & 15;
    const int quad = lane >> 4;
    const int wr   = w >> 1;
    const int wc   = w & 1;
    const long m0  = (long)blockIdx.y * 128;
    const long n0  = (long)blockIdx.x * 128;
    const int kbase = blockIdx.z * K0;
    float* Out = OutBase + (long)blockIdx.z * 4194304;

    const int c0 = w * 64 + lane;
    const int c1 = 256 + c0;
    const int ma0 = c0 >> 2, kca0 = ((c0 & 3) ^ ((ma0 >> 1) & 3)) * 8;
    const int ma1 = c1 >> 2, kca1 = ((c1 & 3) ^ ((ma1 >> 1) & 3)) * 8;

    const u16* Arow0 = Ah + (m0 + ma0) * (long)lda + kbase + kca0;
    const u16* Arow1 = Ah + (m0 + ma1) * (long)lda + kbase + kca1;
    const u16* Brow0 = Bh + (n0 + ma0) * (long)ldb + kbase + kca0;
    const u16* Brow1 = Bh + (n0 + ma1) * (long)ldb + kbase + kca1;
    const u16* Blrow0 = Bl + (n0 + ma0) * (long)ldb + kbase + kca0;
    const u16* Blrow1 = Bl + (n0 + ma1) * (long)ldb + kbase + kca1;

    f32x4 acc[4][4];
    #pragma unroll
    for (int i = 0; i < 4; i++)
        #pragma unroll
        for (int j = 0; j < 4; j++) acc[i][j] = {0.f, 0.f, 0.f, 0.f};

    int caof[4], cbof[4];
    #pragma unroll
    for (int i = 0; i < 4; i++) {
        int m = wr * 64 + i * 16 + r16;
        caof[i] = (m * 4 + (quad ^ ((m >> 1) & 3))) * 8;
        int n = wc * 64 + i * 16 + r16;
        cbof[i] = (n * 4 + (quad ^ ((n >> 1) & 3))) * 8;
    }

    for (int k0 = 0; k0 < K0; k0 += 32) {
        __syncthreads();
        gload_lds16(Arow0 + k0, Ah_l + c0 * 8);
        gload_lds16(Arow1 + k0, Ah_l + c1 * 8);
        gload_lds16(Brow0 + k0, Bh_l + c0 * 8);
        gload_lds16(Brow1 + k0, Bh_l + c1 * 8);
        gload_lds16(Blrow0 + k0, Bl_l + c0 * 8);
        gload_lds16(Blrow1 + k0, Bl_l + c1 * 8);
        __syncthreads();

        bf16x8 fah[4], fbh[4], fbl[4];
        #pragma unroll
        for (int i = 0; i < 4; i++) {
            fah[i] = *(const bf16x8*)(Ah_l + caof[i]);
            fbh[i] = *(const bf16x8*)(Bh_l + cbof[i]);
            fbl[i] = *(const bf16x8*)(Bl_l + cbof[i]);
        }
        #pragma unroll
        for (int i = 0; i < 4; i++) {
            #pragma unroll
            for (int j = 0; j < 4; j++) {
                acc[i][j] = mfma16(fah[i], fbh[j], acc[i][j]);
                acc[i][j] = mfma16(fah[i], fbl[j], acc[i][j]);
            }
        }
    }

    #pragma unroll
    for (int i = 0; i < 4; i++) {
        #pragma unroll
        for (int j = 0; j < 4; j++) {
            long col = n0 + wc * 64 + j * 16 + r16;
            #pragma unroll
            for (int r = 0; r < 4; r++) {
                long row = m0 + wr * 64 + i * 16 + quad * 4 + r;
                Out[row * (long)ldc + col] = acc[i][j][r];
            }
        }
    }
}

// GEMM2 (K=64): 32x32 per wave, 3-term, softplus epilogue
__global__ __launch_bounds__(64)
void gemm_dt32(const u16* __restrict__ Ah, const u16* __restrict__ Al, int lda,
               const u16* __restrict__ Bh, const u16* __restrict__ Bl, int ldb,
               float* __restrict__ C, int ldc, const float* __restrict__ bias)
{
    const int lane = threadIdx.x;
    const int r16  = lane & 15;
    const int quad = lane >> 4;
    const long m0 = (long)blockIdx.y * 32;
    const long n0 = (long)blockIdx.x * 32;

    const u16* Ah0 = Ah + (m0 + r16) * (long)lda + quad * 8;
    const u16* Ah1 = Ah0 + 16L * lda;
    const u16* Al0 = Al + (m0 + r16) * (long)lda + quad * 8;
    const u16* Al1 = Al0 + 16L * lda;
    const u16* Bh0 = Bh + (n0 + r16) * (long)ldb + quad * 8;
    const u16* Bh1 = Bh0 + 16L * ldb;
    const u16* Bl0 = Bl + (n0 + r16) * (long)ldb + quad * 8;
    const u16* Bl1 = Bl0 + 16L * ldb;

    f32x4 acc00 = {0,0,0,0}, acc01 = {0,0,0,0}, acc10 = {0,0,0,0}, acc11 = {0,0,0,0};

    #pragma unroll
    for (int k = 0; k < DT_RANK; k += 32) {
        bf16x8 a0h = *(const bf16x8*)(Ah0 + k);
        bf16x8 a1h = *(const bf16x8*)(Ah1 + k);
        bf16x8 a0l = *(const bf16x8*)(Al0 + k);
        bf16x8 a1l = *(const bf16x8*)(Al1 + k);
        bf16x8 b0h = *(const bf16x8*)(Bh0 + k);
        bf16x8 b1h = *(const bf16x8*)(Bh1 + k);
        bf16x8 b0l = *(const bf16x8*)(Bl0 + k);
        bf16x8 b1l = *(const bf16x8*)(Bl1 + k);
        acc00 = mfma16(a0h, b0h, acc00); acc00 = mfma16(a0h, b0l, acc00); acc00 = mfma16(a0l, b0h, acc00);
        acc01 = mfma16(a0h, b1h, acc01); acc01 = mfma16(a0h, b1l, acc01); acc01 = mfma16(a0l, b1h, acc01);
        acc10 = mfma16(a1h, b0h, acc10); acc10 = mfma16(a1h, b0l, acc10); acc10 = mfma16(a1l, b0h, acc10);
        acc11 = mfma16(a1h, b1h, acc11); acc11 = mfma16(a1h, b1l, acc11); acc11 = mfma16(a1l, b1h, acc11);
    }

    #pragma unroll
    for (int i = 0; i < 2; i++) {
        #pragma unroll
        for (int j = 0; j < 2; j++) {
            f32x4 v = (i == 0) ? (j == 0 ? acc00 : acc01) : (j == 0 ? acc10 : acc11);
            long col = n0 + j * 16 + r16;
            #pragma unroll
            for (int r = 0; r < 4; r++) {
                long row = m0 + i * 16 + quad * 4 + r;
                float x = v[r] + bias[col];
                x = (x > 15.f) ? x : log1pf(__expf(x));
                C[row * (long)ldc + col] = x;
            }
        }
    }
}

// GEMM3: partial[kz] = u @ W_xproj^T over K-slice kz (no atomics)
__global__ __launch_bounds__(64)
void gemm3_skp(const u16* __restrict__ A, int lda,
               const u16* __restrict__ Bh, const u16* __restrict__ Bl, int ldb,
               float* __restrict__ Cpart, int ldc, int K0)
{
    const int lane = threadIdx.x;
    const int r16  = lane & 15;
    const int quad = lane >> 4;
    const long m0 = (long)blockIdx.y * 32;
    const long n0 = (long)blockIdx.x * 32;
    const int kbase = blockIdx.z * K0;
    float* C = Cpart + (long)blockIdx.z * N_XD;

    const u16* Ap0 = A  + (m0 + r16) * (long)lda + quad * 8 + kbase;
    const u16* Ap1 = Ap0 + 16L * lda;
    const u16* Bh0 = Bh + (n0 + r16) * (long)ldb + quad * 8 + kbase;
    const u16* Bh1 = Bh0 + 16L * ldb;
    const u16* Bl0 = Bl + (n0 + r16) * (long)ldb + quad * 8 + kbase;
    const u16* Bl1 = Bl0 + 16L * ldb;

    f32x4 acc00 = {0,0,0,0}, acc01 = {0,0,0,0}, acc10 = {0,0,0,0}, acc11 = {0,0,0,0};

    for (int k = 0; k < K0; k += 32) {
        bf16x8 a0 = *(const bf16x8*)(Ap0 + k);
        bf16x8 a1 = *(const bf16x8*)(Ap1 + k);
        bf16x8 b0h = *(const bf16x8*)(Bh0 + k);
        bf16x8 b1h = *(const bf16x8*)(Bh1 + k);
        bf16x8 b0l = *(const bf16x8*)(Bl0 + k);
        bf16x8 b1l = *(const bf16x8*)(Bl1 + k);
        acc00 = mfma16(a0, b0h, acc00); acc00 = mfma16(a0, b0l, acc00);
        acc01 = mfma16(a0, b1h, acc01); acc01 = mfma16(a0, b1l, acc01);
        acc10 = mfma16(a1, b0h, acc10); acc10 = mfma16(a1, b0l, acc10);
        acc11 = mfma16(a1, b1h, acc11); acc11 = mfma16(a1, b1l, acc11);
    }

    #pragma unroll
    for (int i = 0; i < 2; i++) {
        #pragma unroll
        for (int j = 0; j < 2; j++) {
            f32x4 v = (i == 0) ? (j == 0 ? acc00 : acc01) : (j == 0 ? acc10 : acc11);
            long col = n0 + j * 16 + r16;
            #pragma unroll
            for (int r = 0; r < 4; r++) {
                long row = m0 + i * 16 + quad * 4 + r;
                C[row * (long)ldc + col] = v[r];
            }
        }
    }
}

// combine 8 gemm3 partials -> xdbc f32 + hi/lo split
__global__ __launch_bounds__(256)
void combine3(const float* __restrict__ part, float* __restrict__ xdbc,
              u16* __restrict__ hi, u16* __restrict__ lo)
{
    int i = blockIdx.x * 256 + threadIdx.x;
    if (i >= N_XD) return;
    float s = 0.f;
    #pragma unroll
    for (int j = 0; j < 8; j++) s += part[(long)j * N_XD + i];
    xdbc[i] = s;
    u16 h = f2bf(s);
    hi[i] = h;
    lo[i] = f2bf(s - bf2f(h));
}

// depthwise causal conv(4) + bias + silu, 8 channels per thread
__global__ __launch_bounds__(256)
void conv_silu(const u16* __restrict__ xc, const float* __restrict__ cw,
               const float* __restrict__ cb, u16* __restrict__ u)
{
    long idx = ((long)blockIdx.x * 256 + threadIdx.x) * 8;
    int t  = (int)((idx >> 11) & 2047);
    int d0 = (int)(idx & 2047);

    bf16x8 xrow[4];
    #pragma unroll
    for (int j = 0; j < 4; j++) {
        int tt = t - 3 + j;
        if (tt >= 0) xrow[j] = *(const bf16x8*)(xc + idx + (long)(j - 3) * D_INNER);
        else         xrow[j] = bf16x8{0,0,0,0,0,0,0,0};
    }
    u16x8 out;
    #pragma unroll
    for (int e = 0; e < 8; e++) {
        int d = d0 + e;
        float acc = cb[d];
        #pragma unroll
        for (int j = 0; j < 4; j++)
            acc += cw[d * 4 + j] * (float)xrow[j][e];
        out[e] = f2bf(acc / (1.f + __expf(-acc)));
    }
    *(u16x8*)(u + idx) = out;
}

// ---- chunked parallel scan: pass A ----
__global__ __launch_bounds__(256)
void scan_partA(const float* __restrict__ delta, const u16* __restrict__ u,
                const float* __restrict__ xdbc, const float* __restrict__ A_log,
                float* __restrict__ hbuf, float* __restrict__ sdelta)
{
    const int d = blockIdx.x * 256 + threadIdx.x;
    const int c = blockIdx.y;
    const int b = blockIdx.z;
    const int t0 = c * CHUNK_T;

    float Af[16];
    #pragma unroll
    for (int s = 0; s < 16; s++) Af[s] = -__expf(A_log[d * 16 + s]) * LOG2E;

    float h[16];
    #pragma unroll
    for (int s = 0; s < 16; s++) h[s] = 0.f;
    float sd = 0.f;

    const float* dptr = delta + ((long)b * SEQ + t0) * D_INNER + d;
    const u16*   uptr = u     + ((long)b * SEQ + t0) * D_INNER + d;
    const float* xp   = xdbc  + ((long)b * SEQ + t0) * XPROJ_N;

    for (int t = 0; t < CHUNK_T; t++) {
        float dl = dptr[(long)t * D_INNER];
        float uu = bf2f(uptr[(long)t * D_INNER]);
        f32x4 B0 = *(const f32x4*)(xp + t * XPROJ_N + DT_RANK);
        f32x4 B1 = *(const f32x4*)(xp + t * XPROJ_N + DT_RANK + 4);
        f32x4 B2 = *(const f32x4*)(xp + t * XPROJ_N + DT_RANK + 8);
        f32x4 B3 = *(const f32x4*)(xp + t * XPROJ_N + DT_RANK + 12);
        float Bv[16] = {B0[0],B0[1],B0[2],B0[3], B1[0],B1[1],B1[2],B1[3],
                        B2[0],B2[1],B2[2],B2[3], B3[0],B3[1],B3[2],B3[3]};
        sd += dl;
        float dlu = dl * uu;
        #pragma unroll
        for (int s = 0; s < 16; s++)
            h[s] = h[s] * exp2f(dl * Af[s]) + dlu * Bv[s];
    }

    float* hout = hbuf + ((long)(b * NCHUNK + c) * D_INNER + d) * 16;
    #pragma unroll
    for (int s = 0; s < 16; s++) hout[s] = h[s];
    sdelta[(long)(b * NCHUNK + c) * D_INNER + d] = sd;
}

// ---- pass B: compose chunk boundaries (in-place: hbuf h_end -> h_in) ----
__global__ __launch_bounds__(256)
void scan_fixup(float* __restrict__ hbuf, const float* __restrict__ sdelta,
                const float* __restrict__ A_log)
{
    const int idx = blockIdx.x * 256 + threadIdx.x;
    const int ds = idx & (D_INNER * 16 - 1);
    const int b  = idx >> 15;
    const float Af = -__expf(A_log[ds]) * LOG2E;
    float hin = 0.f;
    #pragma unroll 4
    for (int c = 0; c < NCHUNK; c++) {
        long gi = (long)(b * NCHUNK + c) * (D_INNER * 16) + ds;
        float e = hbuf[gi];
        hbuf[gi] = hin;
        float sd = sdelta[(long)(b * NCHUNK + c) * D_INNER + (ds >> 4)];
        hin = e + exp2f(Af * sd) * hin;
    }
}

// ---- pass C: full scan from h_in, fused +u*D and *silu(z), write y (bf16) ----
__global__ __launch_bounds__(256)
void scan_partC(const float* __restrict__ delta, const u16* __restrict__ u,
                const float* __restrict__ xdbc, const float* __restrict__ z,
                const float* __restrict__ A_log, const float* __restrict__ Dp,
                const float* __restrict__ hbuf, u16* __restrict__ y)
{
    const int d = blockIdx.x * 256 + threadIdx.x;
    const int c = blockIdx.y;
    const int b = blockIdx.z;
    const int t0 = c * CHUNK_T;

    float Af[16];
    #pragma unroll
    for (int s = 0; s < 16; s++) Af[s] = -__expf(A_log[d * 16 + s]) * LOG2E;
    const float Dd = Dp[d];

    float h[16];
    const float* hin = hbuf + ((long)(b * NCHUNK + c) * D_INNER + d) * 16;
    #pragma unroll
    for (int s = 0; s < 16; s++) h[s] = hin[s];

    const float* dptr = delta + ((long)b * SEQ + t0) * D_INNER + d;
    const u16*   uptr = u     + ((long)b * SEQ + t0) * D_INNER + d;
    const float* zptr = z     + ((long)b * SEQ + t0) * D_INNER + d;
    const float* xp   = xdbc  + ((long)b * SEQ + t0) * XPROJ_N;
    u16* yptr = y + ((long)b * SEQ + t0) * D_INNER + d;

    for (int t = 0; t < CHUNK_T; t++) {
        float dl = dptr[(long)t * D_INNER];
        float uu = bf2f(uptr[(long)t * D_INNER]);
        float zl = zptr[(long)t * D_INNER];
        f32x4 B0 = *(const f32x4*)(xp + t * XPROJ_N + DT_RANK);
        f32x4 B1 = *(const f32x4*)(xp + t * XPROJ_N + DT_RANK + 4);
        f32x4 B2 = *(const f32x4*)(xp + t * XPROJ_N + DT_RANK + 8);
        f32x4 B3 = *(const f32x4*)(xp + t * XPROJ_N + DT_RANK + 12);
        f32x4 C0 = *(const f32x4*)(xp + t * XPROJ_N + DT_RANK + 16);
        f32x4 C1 = *(const f32x4*)(xp + t * XPROJ_N + DT_RANK + 20);
        f32x4 C2 = *(const f32x4*)(xp + t * XPROJ_N + DT_RANK + 24);
        f32x4 C3 = *(const f32x4*)(xp + t * XPROJ_N + DT_RANK + 28);
        float Bv[16] = {B0[0],B0[1],B0[2],B0[3], B1[0],B1[1],B1[2],B1[3],
                        B2[0],B2[1],B2[2],B2[3], B3[0],B3[1],B3[2],B3[3]};
        float Cv[16] = {C0[0],C0[1],C0[2],C0[3], C1[0],C1[1],C1[2],C1[3],
                        C2[0],C2[1],C2[2],C2[3], C3[0],C3[1],C3[2],C3[3]};
        float dlu = dl * uu;
        float p0 = 0.f, p1 = 0.f, p2 = 0.f, p3 = 0.f;
        #pragma unroll
        for (int s = 0; s < 16; s += 4) {
            h[s]   = h[s]   * exp2f(dl * Af[s])   + dlu * Bv[s];
            h[s+1] = h[s+1] * exp2f(dl * Af[s+1]) + dlu * Bv[s+1];
            h[s+2] = h[s+2] * exp2f(dl * Af[s+2]) + dlu * Bv[s+2];
            h[s+3] = h[s+3] * exp2f(dl * Af[s+3]) + dlu * Bv[s+3];
            p0 += h[s]   * Cv[s];
            p1 += h[s+1] * Cv[s+1];
            p2 += h[s+2] * Cv[s+2];
            p3 += h[s+3] * Cv[s+3];
        }
        float acc = (p0 + p1) + (p2 + p3);
        float sz = zl / (1.f + __expf(-zl));
        float yy = (acc + uu * Dd) * sz;
        yptr[(long)t * D_INNER] = f2bf(yy);
    }
}

// layernorm over sum of 2 split-K partials
__global__ __launch_bounds__(256)
void layernorm_kernel(const float* __restrict__ pa, const float* __restrict__ pb,
                      const float* __restrict__ gamma, const float* __restrict__ beta,
                      float* __restrict__ out)
{
    const long row = blockIdx.x;
    const long base = row * DIM;
    int tid = threadIdx.x;
    float v[4];
    float sum = 0.f, sq = 0.f;
    #pragma unroll
    for (int i = 0; i < 4; i++) {
        long c = base + tid + i * 256;
        v[i] = pa[c] + pb[c];
        sum += v[i];
        sq  += v[i] * v[i];
    }
    #pragma unroll
    for (int off = 1; off < 64; off <<= 1) {
        sum += __shfl_xor(sum, off);
        sq  += __shfl_xor(sq, off);
    }
    __shared__ float ssum[4], ssq[4];
    int w = tid >> 6;
    if ((tid & 63) == 0) { ssum[w] = sum; ssq[w] = sq; }
    __syncthreads();
    float ts = ssum[0] + ssum[1] + ssum[2] + ssum[3];
    float tq = ssq[0] + ssq[1] + ssq[2] + ssq[3];
    float mean = ts * (1.f / DIM);
    float var  = tq * (1.f / DIM) - mean * mean;
    float rstd = rsqrtf(var + 1e-5f);
    float* o = out + base;
    #pragma unroll
    for (int i = 0; i < 4; i++) {
        int c = tid + i * 256;
        o[c] = (v[i] - mean) * rstd * gamma[c] + beta[c];
    }
}

extern "C" void kernel_launch(void* const* d_in, const int* in_sizes, int n_in,
                              void* d_out, int out_size, void* d_ws, size_t ws_size,
                              hipStream_t stream)
{
    const float* x      = (const float*)d_in[0];
    const float* W_in   = (const float*)d_in[1];
    const float* conv_w = (const float*)d_in[2];
    const float* conv_b = (const float*)d_in[3];
    const float* W_xproj= (const float*)d_in[4];
    const float* W_dt   = (const float*)d_in[5];
    const float* b_dt   = (const float*)d_in[6];
    const float* A_log  = (const float*)d_in[7];
    const float* Dv     = (const float*)d_in[8];
    const float* W_out  = (const float*)d_in[9];
    const float* gamma  = (const float*)d_in[10];
    const float* beta   = (const float*)d_in[11];

    char* ws = (char*)d_ws;
    u16*   xc    = (u16*)(ws);
    float* g3p   = (float*)(ws);
    u16*   xdh   = (u16*)(ws + 12582912);
    u16*   xdl   = (u16*)(ws + 14155776);
    float* hbuf  = (float*)(ws);
    float* sdel  = (float*)(ws + 8388608);
    float* z     = (float*)(ws + 16777216);
    float* opre  = (float*)(ws + 16777216);
    u16*   u     = (u16*)(ws + 50331648);
    u16*   wouth = (u16*)(ws + 50331648);
    u16*   woutl = (u16*)(ws + 54525952);
    u16*   xh    = (u16*)(ws + 67108864);
    u16*   xl    = (u16*)(ws + 75497472);
    u16*   wh    = (u16*)(ws + 83886080);
    u16*   wl    = (u16*)(ws + 92274688);
    float* delta = (float*)(ws + 67108864);
    float* xdbc  = (float*)(ws + 100663296);
    u16*   wxh   = (u16*)(ws + 102236160);
    u16*   wxl   = (u16*)(ws + 102629376);
    u16*   wdth  = (u16*)(ws + 103022592);
    u16*   wdtl  = (u16*)(ws + 103284736);
    u16*   yb    = (u16*)d_out;

    // 0) all pre-splits except W_out in one launch
    megasplit4<<<34048, 256, 0, stream>>>(x, xh, xl, W_in, wh, wl,
                                          W_xproj, wxh, wxl, W_dt, wdth, wdtl);
    // 1) xz = x @ W_in^T -> xc bf16 | z f32   (M=4096,N=4096,K=1024)
    gemm128<3, EPI_XZ><<<dim3(32, 32), 256, 0, stream>>>(
        xh, xl, DIM, wh, wl, DIM, xc, z, 0, DIM, nullptr);
    // 2) u = silu(conv4(xc)+cb)
    conv_silu<<<4096, 256, 0, stream>>>(xc, conv_w, conv_b, u);
    // 3) gemm3 partials (split-K=8) + combine(-> xdbc, xdh, xdl)
    gemm3_skp<<<dim3(3, 128, 8), 64, 0, stream>>>(
        u, D_INNER, wxh, wxl, D_INNER, g3p, XPROJ_N, 256);
    combine3<<<1536, 256, 0, stream>>>(g3p, xdbc, xdh, xdl);
    // 4) delta = softplus(dt @ W_dt^T + b_dt)  (M=4096,N=2048,K=64)
    gemm_dt32<<<dim3(64, 128), 64, 0, stream>>>(
        xdh, xdl, XPROJ_N, wdth, wdtl, DT_RANK, delta, D_INNER, b_dt);
    // 5) chunked parallel scan
    scan_partA<<<dim3(8, NCHUNK, BSZ), 256, 0, stream>>>(delta, u, xdbc, A_log, hbuf, sdel);
    scan_fixup<<<256, 256, 0, stream>>>(hbuf, sdel, A_log);
    scan_partC<<<dim3(8, NCHUNK, BSZ), 256, 0, stream>>>(delta, u, xdbc, z, A_log, Dv, hbuf, yb);
    // 5b) split W_out (into dead u region)
    split_kernel<<<8192, 256, 0, stream>>>(W_out, wouth, woutl, N_WO);
    // 6) opre[kz] = yb @ W_out^T slice  (split-K=2)
    gemm128_sk2<<<dim3(8, 32, 2), 256, 0, stream>>>(
        yb, D_INNER, wouth, woutl, D_INNER, opre, DIM, 1024);
    // 7) layernorm over sum of partials -> d_out f32
    layernorm_kernel<<<4096, 256, 0, stream>>>(
        opre, opre + 4194304, gamma, beta, (float*)d_out);
}

// Round 11
// 451.898 us; speedup vs baseline: 1.0854x; 1.0122x over previous
//
#include <hip/hip_runtime.h>
#include <stdint.h>

typedef unsigned short u16;
typedef __bf16 bf16x8 __attribute__((ext_vector_type(8)));
typedef unsigned short u16x8 __attribute__((ext_vector_type(8)));
typedef unsigned short u16x4 __attribute__((ext_vector_type(4)));
typedef float f32x4 __attribute__((ext_vector_type(4)));

#define BSZ 2
#define SEQ 2048
#define DIM 1024
#define D_INNER 2048
#define DT_RANK 64
#define D_STATE 16
#define XPROJ_N 96   // DT_RANK + 2*D_STATE
#define NCHUNK 32
#define CHUNK_T 64   // SEQ / NCHUNK
#define LOG2E 1.44269504f

#define N_X   4194304
#define N_W   4194304
#define N_WX  196608
#define N_WDT 131072
#define N_WO  2097152
#define N_XD  393216

__device__ __forceinline__ float bf2f(u16 h) {
    return __uint_as_float(((unsigned)h) << 16);
}
__device__ __forceinline__ u16 f2bf(float f) {
    unsigned u = __float_as_uint(f);
    unsigned r = (u + 0x7FFFu + ((u >> 16) & 1u)) >> 16;
    return (u16)r;
}

__device__ __forceinline__ f32x4 mfma16(bf16x8 a, bf16x8 b, f32x4 c) {
    return __builtin_amdgcn_mfma_f32_16x16x32_bf16(a, b, c, 0, 0, 0);
}

__device__ __forceinline__ void gload_lds16(const void* g, void* l) {
    __builtin_amdgcn_global_load_lds(
        (const __attribute__((address_space(1))) unsigned int*)(uintptr_t)g,
        (__attribute__((address_space(3))) unsigned int*)(uintptr_t)l,
        16, 0, 0);
}

// vectorized x4 split: f32x4 -> bf16 hi/lo x4
__device__ __forceinline__ void split4(const float* __restrict__ in,
                                       u16* __restrict__ hi, u16* __restrict__ lo,
                                       long i)
{
    f32x4 v = *(const f32x4*)(in + i);
    u16x4 h, l;
    #pragma unroll
    for (int j = 0; j < 4; j++) {
        u16 hh = f2bf(v[j]);
        h[j] = hh;
        l[j] = f2bf(v[j] - bf2f(hh));
    }
    *(u16x4*)(hi + i) = h;
    *(u16x4*)(lo + i) = l;
}

// split x, W_in, W_xproj, W_dt -> bf16 hi/lo, one launch, x4 vectorized
__global__ __launch_bounds__(256)
void megasplit4(const float* __restrict__ x,  u16* __restrict__ xh,  u16* __restrict__ xl,
                const float* __restrict__ w,  u16* __restrict__ wh,  u16* __restrict__ wl,
                const float* __restrict__ wx, u16* __restrict__ wxh, u16* __restrict__ wxl,
                const float* __restrict__ wd, u16* __restrict__ wdh, u16* __restrict__ wdl)
{
    long i = ((long)blockIdx.x * 256 + threadIdx.x) * 4;
    if (i < N_X) { split4(x, xh, xl, i); return; }
    i -= N_X;
    if (i < N_W) { split4(w, wh, wl, i); return; }
    i -= N_W;
    if (i < N_WX) { split4(wx, wxh, wxl, i); return; }
    i -= N_WX;
    if (i < N_WDT) { split4(wd, wdh, wdl, i); }
}

enum { EPI_XZ = 0, EPI_F32 = 1, EPI_SOFTPLUS = 2 };

// 128x128 tile per 256-thread block, BK=32, global_load_lds staging, swizzled
// LDS, 16x16x32 MFMA. PROVEN: 0 bank conflicts (32x32x16 regressed — R9).
// TERMS=3: ah*bh+ah*bl+al*bh. TERMS=2: a*bh+a*bl.
template<int TERMS, int EPI>
__global__ __launch_bounds__(256)
void gemm128(const u16* __restrict__ Ah, const u16* __restrict__ Al, int lda,
             const u16* __restrict__ Bh, const u16* __restrict__ Bl, int ldb,
             void* __restrict__ C, void* __restrict__ C2, int ldc,
             int K, const float* __restrict__ bias)
{
    __shared__ u16 lds[(TERMS == 3) ? 16384 : 12288];
    u16* Ah_l = lds;
    u16* Al_l = lds + 4096;
    u16* Bh_l = lds + ((TERMS == 3) ? 8192 : 4096);
    u16* Bl_l = lds + ((TERMS == 3) ? 12288 : 8192);

    const int tid  = threadIdx.x;
    const int w    = tid >> 6;
    const int lane = tid & 63;
    const int r16  = lane & 15;
    const int quad = lane >> 4;
    const int wr   = w >> 1;
    const int wc   = w & 1;
    const long m0  = (long)blockIdx.y * 128;
    const long n0  = (long)blockIdx.x * 128;

    const int c0 = w * 64 + lane;
    const int c1 = 256 + c0;
    const int ma0 = c0 >> 2, kca0 = ((c0 & 3) ^ ((ma0 >> 1) & 3)) * 8;
    const int ma1 = c1 >> 2, kca1 = ((c1 & 3) ^ ((ma1 >> 1) & 3)) * 8;

    const u16* Arow0 = Ah + (m0 + ma0) * (long)lda + kca0;
    const u16* Arow1 = Ah + (m0 + ma1) * (long)lda + kca1;
    const u16* Alrow0 = (TERMS == 3) ? Al + (m0 + ma0) * (long)lda + kca0 : nullptr;
    const u16* Alrow1 = (TERMS == 3) ? Al + (m0 + ma1) * (long)lda + kca1 : nullptr;
    const u16* Brow0 = Bh + (n0 + ma0) * (long)ldb + kca0;
    const u16* Brow1 = Bh + (n0 + ma1) * (long)ldb + kca1;
    const u16* Blrow0 = Bl + (n0 + ma0) * (long)ldb + kca0;
    const u16* Blrow1 = Bl + (n0 + ma1) * (long)ldb + kca1;

    f32x4 acc[4][4];
    #pragma unroll
    for (int i = 0; i < 4; i++)
        #pragma unroll
        for (int j = 0; j < 4; j++) acc[i][j] = {0.f, 0.f, 0.f, 0.f};

    int caof[4], cbof[4];
    #pragma unroll
    for (int i = 0; i < 4; i++) {
        int m = wr * 64 + i * 16 + r16;
        caof[i] = (m * 4 + (quad ^ ((m >> 1) & 3))) * 8;
        int n = wc * 64 + i * 16 + r16;
        cbof[i] = (n * 4 + (quad ^ ((n >> 1) & 3))) * 8;
    }

    for (int k0 = 0; k0 < K; k0 += 32) {
        __syncthreads();
        gload_lds16(Arow0 + k0, Ah_l + c0 * 8);
        gload_lds16(Arow1 + k0, Ah_l + c1 * 8);
        if (TERMS == 3) {
            gload_lds16(Alrow0 + k0, Al_l + c0 * 8);
            gload_lds16(Alrow1 + k0, Al_l + c1 * 8);
        }
        gload_lds16(Brow0 + k0, Bh_l + c0 * 8);
        gload_lds16(Brow1 + k0, Bh_l + c1 * 8);
        gload_lds16(Blrow0 + k0, Bl_l + c0 * 8);
        gload_lds16(Blrow1 + k0, Bl_l + c1 * 8);
        __syncthreads();

        bf16x8 fah[4], fal[4], fbh[4], fbl[4];
        #pragma unroll
        for (int i = 0; i < 4; i++) {
            fah[i] = *(const bf16x8*)(Ah_l + caof[i]);
            if (TERMS == 3) fal[i] = *(const bf16x8*)(Al_l + caof[i]);
            fbh[i] = *(const bf16x8*)(Bh_l + cbof[i]);
            fbl[i] = *(const bf16x8*)(Bl_l + cbof[i]);
        }
        #pragma unroll
        for (int i = 0; i < 4; i++) {
            #pragma unroll
            for (int j = 0; j < 4; j++) {
                acc[i][j] = mfma16(fah[i], fbh[j], acc[i][j]);
                acc[i][j] = mfma16(fah[i], fbl[j], acc[i][j]);
                if (TERMS == 3) acc[i][j] = mfma16(fal[i], fbh[j], acc[i][j]);
            }
        }
    }

    #pragma unroll
    for (int i = 0; i < 4; i++) {
        #pragma unroll
        for (int j = 0; j < 4; j++) {
            long col = n0 + wc * 64 + j * 16 + r16;
            #pragma unroll
            for (int r = 0; r < 4; r++) {
                long row = m0 + wr * 64 + i * 16 + quad * 4 + r;
                float x = acc[i][j][r];
                if (EPI == EPI_XZ) {
                    if (col < D_INNER) ((u16*)C)[row * (long)D_INNER + col] = f2bf(x);
                    else ((float*)C2)[row * (long)D_INNER + (col - D_INNER)] = x;
                } else if (EPI == EPI_SOFTPLUS) {
                    x += bias[col];
                    x = (x > 15.f) ? x : log1pf(__expf(x));
                    ((float*)C)[row * (long)ldc + col] = x;
                } else {
                    ((float*)C)[row * (long)ldc + col] = x;
                }
            }
        }
    }
}

// GEMM4 split-K=2: 128x128 tile, TERMS=2, kz slice -> own f32 partial buffer
__global__ __launch_bounds__(256)
void gemm128_sk2(const u16* __restrict__ Ah, int lda,
                 const u16* __restrict__ Bh, const u16* __restrict__ Bl, int ldb,
                 float* __restrict__ OutBase, int ldc, int K0)
{
    __shared__ u16 lds[12288];
    u16* Ah_l = lds;
    u16* Bh_l = lds + 4096;
    u16* Bl_l = lds + 8192;

    const int tid  = threadIdx.x;
    const int w    = tid >> 6;
    const int lane = tid & 63;
    const int r16  = lane & 15;
    const int quad = lane >> 4;
    const int wr   = w >> 1;
    const int wc   = w & 1;
    const long m0  = (long)blockIdx.y * 128;
    const long n0  = (long)blockIdx.x * 128;
    const int kbase = blockIdx.z * K0;
    float* Out = OutBase + (long)blockIdx.z * 4194304;

    const int c0 = w * 64 + lane;
    const int c1 = 256 + c0;
    const int ma0 = c0 >> 2, kca0 = ((c0 & 3) ^ ((ma0 >> 1) & 3)) * 8;
    const int ma1 = c1 >> 2, kca1 = ((c1 & 3) ^ ((ma1 >> 1) & 3)) * 8;

    const u16* Arow0 = Ah + (m0 + ma0) * (long)lda + kbase + kca0;
    const u16* Arow1 = Ah + (m0 + ma1) * (long)lda + kbase + kca1;
    const u16* Brow0 = Bh + (n0 + ma0) * (long)ldb + kbase + kca0;
    const u16* Brow1 = Bh + (n0 + ma1) * (long)ldb + kbase + kca1;
    const u16* Blrow0 = Bl + (n0 + ma0) * (long)ldb + kbase + kca0;
    const u16* Blrow1 = Bl + (n0 + ma1) * (long)ldb + kbase + kca1;

    f32x4 acc[4][4];
    #pragma unroll
    for (int i = 0; i < 4; i++)
        #pragma unroll
        for (int j = 0; j < 4; j++) acc[i][j] = {0.f, 0.f, 0.f, 0.f};

    int caof[4], cbof[4];
    #pragma unroll
    for (int i = 0; i < 4; i++) {
        int m = wr * 64 + i * 16 + r16;
        caof[i] = (m * 4 + (quad ^ ((m >> 1) & 3))) * 8;
        int n = wc * 64 + i * 16 + r16;
        cbof[i] = (n * 4 + (quad ^ ((n >> 1) & 3))) * 8;
    }

    for (int k0 = 0; k0 < K0; k0 += 32) {
        __syncthreads();
        gload_lds16(Arow0 + k0, Ah_l + c0 * 8);
        gload_lds16(Arow1 + k0, Ah_l + c1 * 8);
        gload_lds16(Brow0 + k0, Bh_l + c0 * 8);
        gload_lds16(Brow1 + k0, Bh_l + c1 * 8);
        gload_lds16(Blrow0 + k0, Bl_l + c0 * 8);
        gload_lds16(Blrow1 + k0, Bl_l + c1 * 8);
        __syncthreads();

        bf16x8 fah[4], fbh[4], fbl[4];
        #pragma unroll
        for (int i = 0; i < 4; i++) {
            fah[i] = *(const bf16x8*)(Ah_l + caof[i]);
            fbh[i] = *(const bf16x8*)(Bh_l + cbof[i]);
            fbl[i] = *(const bf16x8*)(Bl_l + cbof[i]);
        }
        #pragma unroll
        for (int i = 0; i < 4; i++) {
            #pragma unroll
            for (int j = 0; j < 4; j++) {
                acc[i][j] = mfma16(fah[i], fbh[j], acc[i][j]);
                acc[i][j] = mfma16(fah[i], fbl[j], acc[i][j]);
            }
        }
    }

    #pragma unroll
    for (int i = 0; i < 4; i++) {
        #pragma unroll
        for (int j = 0; j < 4; j++) {
            long col = n0 + wc * 64 + j * 16 + r16;
            #pragma unroll
            for (int r = 0; r < 4; r++) {
                long row = m0 + wr * 64 + i * 16 + quad * 4 + r;
                Out[row * (long)ldc + col] = acc[i][j][r];
            }
        }
    }
}

// GEMM2 (K=64): 32x32 per wave, 3-term, softplus epilogue
__global__ __launch_bounds__(64)
void gemm_dt32(const u16* __restrict__ Ah, const u16* __restrict__ Al, int lda,
               const u16* __restrict__ Bh, const u16* __restrict__ Bl, int ldb,
               float* __restrict__ C, int ldc, const float* __restrict__ bias)
{
    const int lane = threadIdx.x;
    const int r16  = lane & 15;
    const int quad = lane >> 4;
    const long m0 = (long)blockIdx.y * 32;
    const long n0 = (long)blockIdx.x * 32;

    const u16* Ah0 = Ah + (m0 + r16) * (long)lda + quad * 8;
    const u16* Ah1 = Ah0 + 16L * lda;
    const u16* Al0 = Al + (m0 + r16) * (long)lda + quad * 8;
    const u16* Al1 = Al0 + 16L * lda;
    const u16* Bh0 = Bh + (n0 + r16) * (long)ldb + quad * 8;
    const u16* Bh1 = Bh0 + 16L * ldb;
    const u16* Bl0 = Bl + (n0 + r16) * (long)ldb + quad * 8;
    const u16* Bl1 = Bl0 + 16L * ldb;

    f32x4 acc00 = {0,0,0,0}, acc01 = {0,0,0,0}, acc10 = {0,0,0,0}, acc11 = {0,0,0,0};

    #pragma unroll
    for (int k = 0; k < DT_RANK; k += 32) {
        bf16x8 a0h = *(const bf16x8*)(Ah0 + k);
        bf16x8 a1h = *(const bf16x8*)(Ah1 + k);
        bf16x8 a0l = *(const bf16x8*)(Al0 + k);
        bf16x8 a1l = *(const bf16x8*)(Al1 + k);
        bf16x8 b0h = *(const bf16x8*)(Bh0 + k);
        bf16x8 b1h = *(const bf16x8*)(Bh1 + k);
        bf16x8 b0l = *(const bf16x8*)(Bl0 + k);
        bf16x8 b1l = *(const bf16x8*)(Bl1 + k);
        acc00 = mfma16(a0h, b0h, acc00); acc00 = mfma16(a0h, b0l, acc00); acc00 = mfma16(a0l, b0h, acc00);
        acc01 = mfma16(a0h, b1h, acc01); acc01 = mfma16(a0h, b1l, acc01); acc01 = mfma16(a0l, b1h, acc01);
        acc10 = mfma16(a1h, b0h, acc10); acc10 = mfma16(a1h, b0l, acc10); acc10 = mfma16(a1l, b0h, acc10);
        acc11 = mfma16(a1h, b1h, acc11); acc11 = mfma16(a1h, b1l, acc11); acc11 = mfma16(a1l, b1h, acc11);
    }

    #pragma unroll
    for (int i = 0; i < 2; i++) {
        #pragma unroll
        for (int j = 0; j < 2; j++) {
            f32x4 v = (i == 0) ? (j == 0 ? acc00 : acc01) : (j == 0 ? acc10 : acc11);
            long col = n0 + j * 16 + r16;
            #pragma unroll
            for (int r = 0; r < 4; r++) {
                long row = m0 + i * 16 + quad * 4 + r;
                float x = v[r] + bias[col];
                x = (x > 15.f) ? x : log1pf(__expf(x));
                C[row * (long)ldc + col] = x;
            }
        }
    }
}

// GEMM3: partial[kz] = u @ W_xproj^T over K-slice kz (no atomics)
__global__ __launch_bounds__(64)
void gemm3_skp(const u16* __restrict__ A, int lda,
               const u16* __restrict__ Bh, const u16* __restrict__ Bl, int ldb,
               float* __restrict__ Cpart, int ldc, int K0)
{
    const int lane = threadIdx.x;
    const int r16  = lane & 15;
    const int quad = lane >> 4;
    const long m0 = (long)blockIdx.y * 32;
    const long n0 = (long)blockIdx.x * 32;
    const int kbase = blockIdx.z * K0;
    float* C = Cpart + (long)blockIdx.z * N_XD;

    const u16* Ap0 = A  + (m0 + r16) * (long)lda + quad * 8 + kbase;
    const u16* Ap1 = Ap0 + 16L * lda;
    const u16* Bh0 = Bh + (n0 + r16) * (long)ldb + quad * 8 + kbase;
    const u16* Bh1 = Bh0 + 16L * ldb;
    const u16* Bl0 = Bl + (n0 + r16) * (long)ldb + quad * 8 + kbase;
    const u16* Bl1 = Bl0 + 16L * ldb;

    f32x4 acc00 = {0,0,0,0}, acc01 = {0,0,0,0}, acc10 = {0,0,0,0}, acc11 = {0,0,0,0};

    for (int k = 0; k < K0; k += 32) {
        bf16x8 a0 = *(const bf16x8*)(Ap0 + k);
        bf16x8 a1 = *(const bf16x8*)(Ap1 + k);
        bf16x8 b0h = *(const bf16x8*)(Bh0 + k);
        bf16x8 b1h = *(const bf16x8*)(Bh1 + k);
        bf16x8 b0l = *(const bf16x8*)(Bl0 + k);
        bf16x8 b1l = *(const bf16x8*)(Bl1 + k);
        acc00 = mfma16(a0, b0h, acc00); acc00 = mfma16(a0, b0l, acc00);
        acc01 = mfma16(a0, b1h, acc01); acc01 = mfma16(a0, b1l, acc01);
        acc10 = mfma16(a1, b0h, acc10); acc10 = mfma16(a1, b0l, acc10);
        acc11 = mfma16(a1, b1h, acc11); acc11 = mfma16(a1, b1l, acc11);
    }

    #pragma unroll
    for (int i = 0; i < 2; i++) {
        #pragma unroll
        for (int j = 0; j < 2; j++) {
            f32x4 v = (i == 0) ? (j == 0 ? acc00 : acc01) : (j == 0 ? acc10 : acc11);
            long col = n0 + j * 16 + r16;
            #pragma unroll
            for (int r = 0; r < 4; r++) {
                long row = m0 + i * 16 + quad * 4 + r;
                C[row * (long)ldc + col] = v[r];
            }
        }
    }
}

// combine 8 gemm3 partials -> xdbc f32 + hi/lo split, x4 vectorized
__global__ __launch_bounds__(256)
void combine3(const float* __restrict__ part, float* __restrict__ xdbc,
              u16* __restrict__ hi, u16* __restrict__ lo)
{
    long i = ((long)blockIdx.x * 256 + threadIdx.x) * 4;
    if (i >= N_XD) return;
    f32x4 s = *(const f32x4*)(part + i);
    #pragma unroll
    for (int j = 1; j < 8; j++) {
        f32x4 p = *(const f32x4*)(part + (long)j * N_XD + i);
        s[0] += p[0]; s[1] += p[1]; s[2] += p[2]; s[3] += p[3];
    }
    *(f32x4*)(xdbc + i) = s;
    u16x4 h, l;
    #pragma unroll
    for (int j = 0; j < 4; j++) {
        u16 hh = f2bf(s[j]);
        h[j] = hh;
        l[j] = f2bf(s[j] - bf2f(hh));
    }
    *(u16x4*)(hi + i) = h;
    *(u16x4*)(lo + i) = l;
}

// depthwise causal conv(4) + bias + silu, 8 channels per thread
__global__ __launch_bounds__(256)
void conv_silu(const u16* __restrict__ xc, const float* __restrict__ cw,
               const float* __restrict__ cb, u16* __restrict__ u)
{
    long idx = ((long)blockIdx.x * 256 + threadIdx.x) * 8;
    int t  = (int)((idx >> 11) & 2047);
    int d0 = (int)(idx & 2047);

    bf16x8 xrow[4];
    #pragma unroll
    for (int j = 0; j < 4; j++) {
        int tt = t - 3 + j;
        if (tt >= 0) xrow[j] = *(const bf16x8*)(xc + idx + (long)(j - 3) * D_INNER);
        else         xrow[j] = bf16x8{0,0,0,0,0,0,0,0};
    }
    u16x8 out;
    #pragma unroll
    for (int e = 0; e < 8; e++) {
        int d = d0 + e;
        float acc = cb[d];
        #pragma unroll
        for (int j = 0; j < 4; j++)
            acc += cw[d * 4 + j] * (float)xrow[j][e];
        out[e] = f2bf(acc / (1.f + __expf(-acc)));
    }
    *(u16x8*)(u + idx) = out;
}

// ---- chunked parallel scan: pass A  (+ fused W_out hi/lo split) ----
__global__ __launch_bounds__(256)
void scan_partA(const float* __restrict__ delta, const u16* __restrict__ u,
                const float* __restrict__ xdbc, const float* __restrict__ A_log,
                float* __restrict__ hbuf, float* __restrict__ sdelta,
                const float* __restrict__ wout, u16* __restrict__ wouth,
                u16* __restrict__ woutl)
{
    const int d = blockIdx.x * 256 + threadIdx.x;
    const int c = blockIdx.y;
    const int b = blockIdx.z;
    const int t0 = c * CHUNK_T;

    float Af[16];
    #pragma unroll
    for (int s = 0; s < 16; s++) Af[s] = -__expf(A_log[d * 16 + s]) * LOG2E;

    float h[16];
    #pragma unroll
    for (int s = 0; s < 16; s++) h[s] = 0.f;
    float sd = 0.f;

    const float* dptr = delta + ((long)b * SEQ + t0) * D_INNER + d;
    const u16*   uptr = u     + ((long)b * SEQ + t0) * D_INNER + d;
    const float* xp   = xdbc  + ((long)b * SEQ + t0) * XPROJ_N;

    for (int t = 0; t < CHUNK_T; t++) {
        float dl = dptr[(long)t * D_INNER];
        float uu = bf2f(uptr[(long)t * D_INNER]);
        f32x4 B0 = *(const f32x4*)(xp + t * XPROJ_N + DT_RANK);
        f32x4 B1 = *(const f32x4*)(xp + t * XPROJ_N + DT_RANK + 4);
        f32x4 B2 = *(const f32x4*)(xp + t * XPROJ_N + DT_RANK + 8);
        f32x4 B3 = *(const f32x4*)(xp + t * XPROJ_N + DT_RANK + 12);
        float Bv[16] = {B0[0],B0[1],B0[2],B0[3], B1[0],B1[1],B1[2],B1[3],
                        B2[0],B2[1],B2[2],B2[3], B3[0],B3[1],B3[2],B3[3]};
        sd += dl;
        float dlu = dl * uu;
        #pragma unroll
        for (int s = 0; s < 16; s++)
            h[s] = h[s] * exp2f(dl * Af[s]) + dlu * Bv[s];
    }

    float* hout = hbuf + ((long)(b * NCHUNK + c) * D_INNER + d) * 16;
    #pragma unroll
    for (int s = 0; s < 16; s++) hout[s] = h[s];
    sdelta[(long)(b * NCHUNK + c) * D_INNER + d] = sd;

    // fused W_out split: 131072 threads x 16 elems = 2097152 (exact)
    long tidg = (((long)b * NCHUNK + c) * 8 + blockIdx.x) * 256 + threadIdx.x;
    long base = tidg * 16;
    #pragma unroll
    for (int k = 0; k < 4; k++) split4(wout, wouth, woutl, base + 4 * k);
}

// ---- pass B: compose chunk boundaries (in-place: hbuf h_end -> h_in) ----
__global__ __launch_bounds__(256)
void scan_fixup(float* __restrict__ hbuf, const float* __restrict__ sdelta,
                const float* __restrict__ A_log)
{
    const int idx = blockIdx.x * 256 + threadIdx.x;
    const int ds = idx & (D_INNER * 16 - 1);
    const int b  = idx >> 15;
    const float Af = -__expf(A_log[ds]) * LOG2E;
    float hin = 0.f;
    #pragma unroll 4
    for (int c = 0; c < NCHUNK; c++) {
        long gi = (long)(b * NCHUNK + c) * (D_INNER * 16) + ds;
        float e = hbuf[gi];
        hbuf[gi] = hin;
        float sd = sdelta[(long)(b * NCHUNK + c) * D_INNER + (ds >> 4)];
        hin = e + exp2f(Af * sd) * hin;
    }
}

// ---- pass C: full scan from h_in, fused +u*D and *silu(z), write y (bf16) ----
__global__ __launch_bounds__(256)
void scan_partC(const float* __restrict__ delta, const u16* __restrict__ u,
                const float* __restrict__ xdbc, const float* __restrict__ z,
                const float* __restrict__ A_log, const float* __restrict__ Dp,
                const float* __restrict__ hbuf, u16* __restrict__ y)
{
    const int d = blockIdx.x * 256 + threadIdx.x;
    const int c = blockIdx.y;
    const int b = blockIdx.z;
    const int t0 = c * CHUNK_T;

    float Af[16];
    #pragma unroll
    for (int s = 0; s < 16; s++) Af[s] = -__expf(A_log[d * 16 + s]) * LOG2E;
    const float Dd = Dp[d];

    float h[16];
    const float* hin = hbuf + ((long)(b * NCHUNK + c) * D_INNER + d) * 16;
    #pragma unroll
    for (int s = 0; s < 16; s++) h[s] = hin[s];

    const float* dptr = delta + ((long)b * SEQ + t0) * D_INNER + d;
    const u16*   uptr = u     + ((long)b * SEQ + t0) * D_INNER + d;
    const float* zptr = z     + ((long)b * SEQ + t0) * D_INNER + d;
    const float* xp   = xdbc  + ((long)b * SEQ + t0) * XPROJ_N;
    u16* yptr = y + ((long)b * SEQ + t0) * D_INNER + d;

    for (int t = 0; t < CHUNK_T; t++) {
        float dl = dptr[(long)t * D_INNER];
        float uu = bf2f(uptr[(long)t * D_INNER]);
        float zl = zptr[(long)t * D_INNER];
        f32x4 B0 = *(const f32x4*)(xp + t * XPROJ_N + DT_RANK);
        f32x4 B1 = *(const f32x4*)(xp + t * XPROJ_N + DT_RANK + 4);
        f32x4 B2 = *(const f32x4*)(xp + t * XPROJ_N + DT_RANK + 8);
        f32x4 B3 = *(const f32x4*)(xp + t * XPROJ_N + DT_RANK + 12);
        f32x4 C0 = *(const f32x4*)(xp + t * XPROJ_N + DT_RANK + 16);
        f32x4 C1 = *(const f32x4*)(xp + t * XPROJ_N + DT_RANK + 20);
        f32x4 C2 = *(const f32x4*)(xp + t * XPROJ_N + DT_RANK + 24);
        f32x4 C3 = *(const f32x4*)(xp + t * XPROJ_N + DT_RANK + 28);
        float Bv[16] = {B0[0],B0[1],B0[2],B0[3], B1[0],B1[1],B1[2],B1[3],
                        B2[0],B2[1],B2[2],B2[3], B3[0],B3[1],B3[2],B3[3]};
        float Cv[16] = {C0[0],C0[1],C0[2],C0[3], C1[0],C1[1],C1[2],C1[3],
                        C2[0],C2[1],C2[2],C2[3], C3[0],C3[1],C3[2],C3[3]};
        float dlu = dl * uu;
        float p0 = 0.f, p1 = 0.f, p2 = 0.f, p3 = 0.f;
        #pragma unroll
        for (int s = 0; s < 16; s += 4) {
            h[s]   = h[s]   * exp2f(dl * Af[s])   + dlu * Bv[s];
            h[s+1] = h[s+1] * exp2f(dl * Af[s+1]) + dlu * Bv[s+1];
            h[s+2] = h[s+2] * exp2f(dl * Af[s+2]) + dlu * Bv[s+2];
            h[s+3] = h[s+3] * exp2f(dl * Af[s+3]) + dlu * Bv[s+3];
            p0 += h[s]   * Cv[s];
            p1 += h[s+1] * Cv[s+1];
            p2 += h[s+2] * Cv[s+2];
            p3 += h[s+3] * Cv[s+3];
        }
        float acc = (p0 + p1) + (p2 + p3);
        float sz = zl / (1.f + __expf(-zl));
        float yy = (acc + uu * Dd) * sz;
        yptr[(long)t * D_INNER] = f2bf(yy);
    }
}

// layernorm over sum of 2 split-K partials
__global__ __launch_bounds__(256)
void layernorm_kernel(const float* __restrict__ pa, const float* __restrict__ pb,
                      const float* __restrict__ gamma, const float* __restrict__ beta,
                      float* __restrict__ out)
{
    const long row = blockIdx.x;
    const long base = row * DIM;
    int tid = threadIdx.x;
    float v[4];
    float sum = 0.f, sq = 0.f;
    #pragma unroll
    for (int i = 0; i < 4; i++) {
        long c = base + tid + i * 256;
        v[i] = pa[c] + pb[c];
        sum += v[i];
        sq  += v[i] * v[i];
    }
    #pragma unroll
    for (int off = 1; off < 64; off <<= 1) {
        sum += __shfl_xor(sum, off);
        sq  += __shfl_xor(sq, off);
    }
    __shared__ float ssum[4], ssq[4];
    int w = tid >> 6;
    if ((tid & 63) == 0) { ssum[w] = sum; ssq[w] = sq; }
    __syncthreads();
    float ts = ssum[0] + ssum[1] + ssum[2] + ssum[3];
    float tq = ssq[0] + ssq[1] + ssq[2] + ssq[3];
    float mean = ts * (1.f / DIM);
    float var  = tq * (1.f / DIM) - mean * mean;
    float rstd = rsqrtf(var + 1e-5f);
    float* o = out + base;
    #pragma unroll
    for (int i = 0; i < 4; i++) {
        int c = tid + i * 256;
        o[c] = (v[i] - mean) * rstd * gamma[c] + beta[c];
    }
}

extern "C" void kernel_launch(void* const* d_in, const int* in_sizes, int n_in,
                              void* d_out, int out_size, void* d_ws, size_t ws_size,
                              hipStream_t stream)
{
    const float* x      = (const float*)d_in[0];
    const float* W_in   = (const float*)d_in[1];
    const float* conv_w = (const float*)d_in[2];
    const float* conv_b = (const float*)d_in[3];
    const float* W_xproj= (const float*)d_in[4];
    const float* W_dt   = (const float*)d_in[5];
    const float* b_dt   = (const float*)d_in[6];
    const float* A_log  = (const float*)d_in[7];
    const float* Dv     = (const float*)d_in[8];
    const float* W_out  = (const float*)d_in[9];
    const float* gamma  = (const float*)d_in[10];
    const float* beta   = (const float*)d_in[11];

    char* ws = (char*)d_ws;
    // [0,16.78M): xc (s1-2) -> g3p (s3) / xdh,xdl (s3.5-4) -> hbuf + W_out splits (s5+)
    u16*   xc    = (u16*)(ws);
    float* g3p   = (float*)(ws);                 // 8 x 1.57 MB
    u16*   xdh   = (u16*)(ws + 12582912);
    u16*   xdl   = (u16*)(ws + 14155776);
    float* hbuf  = (float*)(ws);                 // 8.39 MB (s5+)
    u16*   wouth = (u16*)(ws + 8388608);         // 4.19 MB (written in scanA, s5)
    u16*   woutl = (u16*)(ws + 12582912);        // 4.19 MB (xdh/xdl dead by s5)
    // [16.78M,50.33M): z (s1->s5C) -> opre partials (s6-7)
    float* z     = (float*)(ws + 16777216);
    float* opre  = (float*)(ws + 16777216);
    // [50.33M,67.11M): u (s2->s5C)
    u16*   u     = (u16*)(ws + 50331648);
    // [67.11M,100.66M): x/W_in splits (s0-1) -> delta (s4->s5C)
    u16*   xh    = (u16*)(ws + 67108864);
    u16*   xl    = (u16*)(ws + 75497472);
    u16*   wh    = (u16*)(ws + 83886080);
    u16*   wl    = (u16*)(ws + 92274688);
    float* delta = (float*)(ws + 67108864);
    // [100.66M,104.07M): xdbc + persistent small splits + sdel
    float* xdbc  = (float*)(ws + 100663296);
    u16*   wxh   = (u16*)(ws + 102236160);
    u16*   wxl   = (u16*)(ws + 102629376);
    u16*   wdth  = (u16*)(ws + 103022592);
    u16*   wdtl  = (u16*)(ws + 103284736);
    float* sdel  = (float*)(ws + 103546880);     // 0.52 MB, ends 104.07 MB (< proven 106.4)
    u16*   yb    = (u16*)d_out;

    // 0) pre-splits (x, W_in, W_xproj, W_dt), x4 vectorized, one launch
    megasplit4<<<8512, 256, 0, stream>>>(x, xh, xl, W_in, wh, wl,
                                         W_xproj, wxh, wxl, W_dt, wdth, wdtl);
    // 1) xz = x @ W_in^T -> xc bf16 | z f32   (M=4096,N=4096,K=1024)
    gemm128<3, EPI_XZ><<<dim3(32, 32), 256, 0, stream>>>(
        xh, xl, DIM, wh, wl, DIM, xc, z, 0, DIM, nullptr);
    // 2) u = silu(conv4(xc)+cb)
    conv_silu<<<4096, 256, 0, stream>>>(xc, conv_w, conv_b, u);
    // 3) gemm3 partials (split-K=8) + combine(-> xdbc, xdh, xdl)
    gemm3_skp<<<dim3(3, 128, 8), 64, 0, stream>>>(
        u, D_INNER, wxh, wxl, D_INNER, g3p, XPROJ_N, 256);
    combine3<<<384, 256, 0, stream>>>(g3p, xdbc, xdh, xdl);
    // 4) delta = softplus(dt @ W_dt^T + b_dt)  (M=4096,N=2048,K=64)
    gemm_dt32<<<dim3(64, 128), 64, 0, stream>>>(
        xdh, xdl, XPROJ_N, wdth, wdtl, DT_RANK, delta, D_INNER, b_dt);
    // 5) chunked parallel scan (partA also splits W_out -> wouth/woutl)
    scan_partA<<<dim3(8, NCHUNK, BSZ), 256, 0, stream>>>(
        delta, u, xdbc, A_log, hbuf, sdel, W_out, wouth, woutl);
    scan_fixup<<<256, 256, 0, stream>>>(hbuf, sdel, A_log);
    scan_partC<<<dim3(8, NCHUNK, BSZ), 256, 0, stream>>>(delta, u, xdbc, z, A_log, Dv, hbuf, yb);
    // 6) opre[kz] = yb @ W_out^T slice  (split-K=2)
    gemm128_sk2<<<dim3(8, 32, 2), 256, 0, stream>>>(
        yb, D_INNER, wouth, woutl, D_INNER, opre, DIM, 1024);
    // 7) layernorm over sum of partials -> d_out f32
    layernorm_kernel<<<4096, 256, 0, stream>>>(
        opre, opre + 4194304, gamma, beta, (float*)d_out);
}